// Round 5
// baseline (308.641 us; speedup 1.0000x reference)
//
#include <hip/hip_runtime.h>

// MultiHeadAttention: B=2, S=2048, H=1024, NH=16, HD=64
// Pipeline: [convert f32->f16] -> [fused QKV GEMM (V transposed)] ->
//           [flash attention] -> [output GEMM f32]
// (identical source; rounds 1-4 all died on an unresponsive container lease)

#define BD 2
#define SD 2048
#define HDIM 1024
#define NHD 16
#define HDD 64
#define NTOK 4096  // BD*SD

typedef float f32x4 __attribute__((ext_vector_type(4)));
typedef _Float16 f16x8 __attribute__((ext_vector_type(8)));
typedef _Float16 f16x4 __attribute__((ext_vector_type(4)));

__device__ __forceinline__ f32x4 mfma_f16(f16x8 a, f16x8 b, f32x4 c) {
  return __builtin_amdgcn_mfma_f32_16x16x32_f16(a, b, c, 0, 0, 0);
}

// ---------------- convert f32 -> f16 ----------------
// dst layout (f16 elems): [x 4M][wq 1M][wk 1M][wv 1M][wo 1M]
__global__ void convert_kernel(const float* __restrict__ x,
                               const float* __restrict__ wq, const float* __restrict__ wk,
                               const float* __restrict__ wv, const float* __restrict__ wo,
                               _Float16* __restrict__ dst) {
  const int total4 = (8 * 1024 * 1024) / 4;
  for (int idx = blockIdx.x * blockDim.x + threadIdx.x; idx < total4;
       idx += gridDim.x * blockDim.x) {
    int e = idx * 4;
    const float* s;
    if (e < 4 * 1024 * 1024) {
      s = x + e;
    } else {
      int w = (e - 4 * 1024 * 1024) >> 20;
      int off = e & 1048575;
      s = (w == 0 ? wq : w == 1 ? wk : w == 2 ? wv : wo) + off;
    }
    float4 v = *(const float4*)s;
    f16x4 h;
    h[0] = (_Float16)v.x; h[1] = (_Float16)v.y;
    h[2] = (_Float16)v.z; h[3] = (_Float16)v.w;
    *(f16x4*)(dst + e) = h;
  }
}

// ---------------- 128x128 GEMM mainloop (C = A * B^T form) ----------------
// C[i][j] = sum_k A[i][k] * B[j][k], K = 1024, BK = 32.
// 256 threads = 4 waves in 2x2; each wave 64x64 (4x4 MFMA 16x16x32 frags).
__device__ __forceinline__ void gemm_mainloop(
    const _Float16* __restrict__ Ap, const _Float16* __restrict__ Bp,
    int i0, int j0, _Float16* As, _Float16* Bs, f32x4 acc[4][4]) {
  const int tid = threadIdx.x;
  const int wid = tid >> 6, lane = tid & 63;
  const int lr = lane & 15, lg = lane >> 4;
  const int wm = wid >> 1, wn = wid & 1;
  // staging: each wave-instr fills 1KB of LDS (16 rows x 64B); lane -> row lane>>2, col (lane&3)*8
  const int srow = lane >> 2;
  const int scol = (lane & 3) * 8;

  for (int k0 = 0; k0 < HDIM; k0 += 32) {
#pragma unroll
    for (int it = 0; it < 2; ++it) {
      int rb = (wid * 2 + it) * 16;
      const _Float16* ga = Ap + (size_t)(i0 + rb + srow) * HDIM + k0 + scol;
      const _Float16* gb = Bp + (size_t)(j0 + rb + srow) * HDIM + k0 + scol;
      __builtin_amdgcn_global_load_lds(
          (__attribute__((address_space(1))) void*)ga,
          (__attribute__((address_space(3))) void*)(As + (wid * 2 + it) * 512), 16, 0, 0);
      __builtin_amdgcn_global_load_lds(
          (__attribute__((address_space(1))) void*)gb,
          (__attribute__((address_space(3))) void*)(Bs + (wid * 2 + it) * 512), 16, 0, 0);
    }
    __syncthreads();  // drains vmcnt: LDS data ready
    f16x8 af[4], bf[4];
#pragma unroll
    for (int mt = 0; mt < 4; mt++)
      af[mt] = *(const f16x8*)(As + (wm * 64 + mt * 16 + lr) * 32 + lg * 8);
#pragma unroll
    for (int nt = 0; nt < 4; nt++)
      bf[nt] = *(const f16x8*)(Bs + (wn * 64 + nt * 16 + lr) * 32 + lg * 8);
#pragma unroll
    for (int mt = 0; mt < 4; mt++)
#pragma unroll
      for (int nt = 0; nt < 4; nt++)
        acc[mt][nt] = mfma_f16(af[mt], bf[nt], acc[mt][nt]);
    __syncthreads();  // all reads done before next stage overwrites
  }
}

// ---------------- fused QKV projection ----------------
// blocks 0..255: Q = x @ Wq^T  (tiles 32x8)
// blocks 256..511: K = x @ Wk^T
// blocks 512..767: V^T = Wv @ x^T  (output written [bh][d][s], coalesced along s)
__global__ __launch_bounds__(256) void gemm_qkv(
    const _Float16* __restrict__ xb,
    const _Float16* __restrict__ wqb, const _Float16* __restrict__ wkb,
    const _Float16* __restrict__ wvb,
    const float* __restrict__ bq, const float* __restrict__ bk,
    const float* __restrict__ bv,
    _Float16* __restrict__ Qo, _Float16* __restrict__ Ko, _Float16* __restrict__ Vt) {
  __shared__ __attribute__((aligned(16))) _Float16 As[128 * 32];
  __shared__ __attribute__((aligned(16))) _Float16 Bs[128 * 32];
  const int bx = blockIdx.x;
  const int mat = bx >> 8;  // 0=Q, 1=K, 2=V
  const int sub = bx & 255;
  const _Float16 *Ap, *Bp;
  int i0, j0;
  if (mat < 2) {
    Ap = xb; Bp = (mat ? wkb : wqb);
    i0 = (sub >> 3) * 128;  // token tile
    j0 = (sub & 7) * 128;   // out-col tile
  } else {
    Ap = wvb; Bp = xb;
    i0 = (sub & 7) * 128;   // weight-row tile (h*64+d)
    j0 = (sub >> 3) * 128;  // token tile
  }
  f32x4 acc[4][4];
#pragma unroll
  for (int a = 0; a < 4; a++)
#pragma unroll
    for (int b = 0; b < 4; b++) acc[a][b] = (f32x4){0.f, 0.f, 0.f, 0.f};

  gemm_mainloop(Ap, Bp, i0, j0, As, Bs, acc);

  const int tid = threadIdx.x;
  const int wid = tid >> 6, lane = tid & 63;
  const int lr = lane & 15, lg = lane >> 4;
  const int wm = wid >> 1, wn = wid & 1;
  const float* bias = (mat == 0 ? bq : mat == 1 ? bk : bv);

#pragma unroll
  for (int mt = 0; mt < 4; mt++) {
#pragma unroll
    for (int nt = 0; nt < 4; nt++) {
      int i = i0 + wm * 64 + mt * 16 + 4 * lg;  // + r
      int j = j0 + wn * 64 + nt * 16 + lr;
      if (mat < 2) {
        float bj = bias[j];
        int h = j >> 6, d = j & 63;
        _Float16* dst = (mat ? Ko : Qo);
#pragma unroll
        for (int r = 0; r < 4; r++) {
          int tok = i + r;
          int b = tok >> 11, s = tok & 2047;
          dst[(((size_t)(b * NHD + h)) * SD + s) * HDD + d] =
              (_Float16)(acc[mt][nt][r] + bj);
        }
      } else {
        int tok = j;
        int b = tok >> 11, s = tok & 2047;
#pragma unroll
        for (int r = 0; r < 4; r++) {
          int wr = i + r;  // weight row = h*64+d
          int h = wr >> 6, d = wr & 63;
          Vt[((size_t)(b * NHD + h) * HDD + d) * SD + s] =
              (_Float16)(acc[mt][nt][r] + bias[wr]);
        }
      }
    }
  }
}

// ---------------- output projection: out = attn @ Wo^T + bo (f32) ----------------
__global__ __launch_bounds__(256) void gemm_out(
    const _Float16* __restrict__ attn, const _Float16* __restrict__ wob,
    const float* __restrict__ bo, float* __restrict__ out) {
  __shared__ __attribute__((aligned(16))) _Float16 As[128 * 32];
  __shared__ __attribute__((aligned(16))) _Float16 Bs[128 * 32];
  const int sub = blockIdx.x;
  const int i0 = (sub >> 3) * 128, j0 = (sub & 7) * 128;
  f32x4 acc[4][4];
#pragma unroll
  for (int a = 0; a < 4; a++)
#pragma unroll
    for (int b = 0; b < 4; b++) acc[a][b] = (f32x4){0.f, 0.f, 0.f, 0.f};

  gemm_mainloop(attn, wob, i0, j0, As, Bs, acc);

  const int tid = threadIdx.x;
  const int wid = tid >> 6, lane = tid & 63;
  const int lr = lane & 15, lg = lane >> 4;
  const int wm = wid >> 1, wn = wid & 1;
#pragma unroll
  for (int mt = 0; mt < 4; mt++) {
#pragma unroll
    for (int nt = 0; nt < 4; nt++) {
      int i = i0 + wm * 64 + mt * 16 + 4 * lg;
      int j = j0 + wn * 64 + nt * 16 + lr;
      float bj = bo[j];
#pragma unroll
      for (int r = 0; r < 4; r++)
        out[(size_t)(i + r) * HDIM + j] = acc[mt][nt][r] + bj;
    }
  }
}

// ---------------- flash attention ----------------
// grid (32 qblocks, 32 heads), 256 threads = 4 waves; each wave owns 16 q-rows.
// K read [bh][s][d]; V read transposed [bh][d][s]; P staged per-wave in LDS.
__global__ __launch_bounds__(256) void attn_kernel(
    const _Float16* __restrict__ Q, const _Float16* __restrict__ K,
    const _Float16* __restrict__ VT, _Float16* __restrict__ AO) {
  const int bh = blockIdx.y, qb = blockIdx.x;
  const int tid = threadIdx.x, wv = tid >> 6, lane = tid & 63;
  const int lr = lane & 15, lg = lane >> 4;
  const int q0 = qb * 64 + wv * 16;
  const _Float16* Qh = Q + (size_t)bh * SD * HDD;
  const _Float16* Kh = K + (size_t)bh * SD * HDD;
  const _Float16* Vh = VT + (size_t)bh * HDD * SD;
  __shared__ __attribute__((aligned(16))) _Float16 P_lds[4][16][64];

  f16x8 qf[2];
#pragma unroll
  for (int kf = 0; kf < 2; kf++)
    qf[kf] = *(const f16x8*)(Qh + (size_t)(q0 + lr) * HDD + kf * 32 + lg * 8);

  f32x4 acc[4];
  float mrun[4], lsum[4];
#pragma unroll
  for (int i = 0; i < 4; i++) {
    acc[i] = (f32x4){0.f, 0.f, 0.f, 0.f};
    mrun[i] = -1e30f;
    lsum[i] = 0.f;
  }
  const float cfac = 0.125f * 1.4426950408889634f;  // 1/sqrt(64) * log2(e)

  for (int kv = 0; kv < SD; kv += 64) {
    // ---- S = Q K^T (rows=q, cols=key) ----
    f32x4 sc[4];
#pragma unroll
    for (int nt = 0; nt < 4; nt++) sc[nt] = (f32x4){0.f, 0.f, 0.f, 0.f};
#pragma unroll
    for (int nt = 0; nt < 4; nt++) {
#pragma unroll
      for (int kf = 0; kf < 2; kf++) {
        f16x8 kfr = *(const f16x8*)(Kh + (size_t)(kv + nt * 16 + lr) * HDD + kf * 32 + lg * 8);
        sc[nt] = mfma_f16(qf[kf], kfr, sc[nt]);
      }
    }
    // ---- online softmax (row = 4*lg + r, col = nt*16 + lr) ----
    float tv[4][4];
#pragma unroll
    for (int nt = 0; nt < 4; nt++)
#pragma unroll
      for (int r = 0; r < 4; r++) tv[nt][r] = sc[nt][r] * cfac;
    float tmax[4];
#pragma unroll
    for (int r = 0; r < 4; r++)
      tmax[r] = fmaxf(fmaxf(tv[0][r], tv[1][r]), fmaxf(tv[2][r], tv[3][r]));
#pragma unroll
    for (int off = 1; off < 16; off <<= 1)
#pragma unroll
      for (int r = 0; r < 4; r++) tmax[r] = fmaxf(tmax[r], __shfl_xor(tmax[r], off));
    float fmul[4], rs[4];
#pragma unroll
    for (int r = 0; r < 4; r++) {
      float mn = fmaxf(mrun[r], tmax[r]);
      fmul[r] = exp2f(mrun[r] - mn);
      mrun[r] = mn;
      rs[r] = 0.f;
    }
    float p[4][4];
#pragma unroll
    for (int nt = 0; nt < 4; nt++)
#pragma unroll
      for (int r = 0; r < 4; r++) {
        p[nt][r] = exp2f(tv[nt][r] - mrun[r]);
        rs[r] += p[nt][r];
      }
#pragma unroll
    for (int off = 1; off < 16; off <<= 1)
#pragma unroll
      for (int r = 0; r < 4; r++) rs[r] += __shfl_xor(rs[r], off);
#pragma unroll
    for (int r = 0; r < 4; r++) lsum[r] = lsum[r] * fmul[r] + rs[r];
#pragma unroll
    for (int ntd = 0; ntd < 4; ntd++)
#pragma unroll
      for (int r = 0; r < 4; r++) acc[ntd][r] *= fmul[r];
    // ---- stage P (per-wave region) ----
#pragma unroll
    for (int nt = 0; nt < 4; nt++)
#pragma unroll
      for (int r = 0; r < 4; r++)
        P_lds[wv][lg * 4 + r][nt * 16 + lr] = (_Float16)p[nt][r];
    __syncthreads();
    // ---- O += P V ----
#pragma unroll
    for (int kf = 0; kf < 2; kf++) {
      f16x8 pf = *(const f16x8*)&P_lds[wv][lr][kf * 32 + lg * 8];
#pragma unroll
      for (int ntd = 0; ntd < 4; ntd++) {
        f16x8 vf = *(const f16x8*)(Vh + (size_t)(ntd * 16 + lr) * SD + kv + kf * 32 + lg * 8);
        acc[ntd] = mfma_f16(pf, vf, acc[ntd]);
      }
    }
    __syncthreads();
  }
  // ---- epilogue: normalize, write attn output [token][H] as f16 ----
  const int b = bh >> 4, h = bh & 15;
#pragma unroll
  for (int r = 0; r < 4; r++) {
    float inv = 1.0f / lsum[r];
    int srow = q0 + lg * 4 + r;
#pragma unroll
    for (int ntd = 0; ntd < 4; ntd++) {
      int col = h * 64 + ntd * 16 + lr;
      AO[((size_t)(b * SD + srow)) * HDIM + col] = (_Float16)(acc[ntd][r] * inv);
    }
  }
}

extern "C" void kernel_launch(void* const* d_in, const int* in_sizes, int n_in,
                              void* d_out, int out_size, void* d_ws, size_t ws_size,
                              hipStream_t stream) {
  const float* x  = (const float*)d_in[0];
  const float* Wq = (const float*)d_in[1];
  const float* bq = (const float*)d_in[2];
  const float* Wk = (const float*)d_in[3];
  const float* bk = (const float*)d_in[4];
  const float* Wv = (const float*)d_in[5];
  const float* bv = (const float*)d_in[6];
  const float* Wo = (const float*)d_in[7];
  const float* bo = (const float*)d_in[8];
  float* out = (float*)d_out;

  _Float16* xb  = (_Float16*)d_ws;            // 4M
  _Float16* wqb = xb + 4 * 1024 * 1024;       // 1M
  _Float16* wkb = wqb + 1024 * 1024;
  _Float16* wvb = wkb + 1024 * 1024;
  _Float16* wob = wvb + 1024 * 1024;
  _Float16* Qb  = wob + 1024 * 1024;          // 4M  [bh][s][d]
  _Float16* Kb  = Qb + 4 * 1024 * 1024;       // 4M  [bh][s][d]
  _Float16* Vt  = Kb + 4 * 1024 * 1024;       // 4M  [bh][d][s]
  _Float16* AOb = Vt + 4 * 1024 * 1024;       // 4M  [token][H]

  convert_kernel<<<dim3(1024), dim3(256), 0, stream>>>(x, Wq, Wk, Wv, Wo, xb);
  gemm_qkv<<<dim3(768), dim3(256), 0, stream>>>(xb, wqb, wkb, wvb, bq, bk, bv, Qb, Kb, Vt);
  attn_kernel<<<dim3(32, 32), dim3(256), 0, stream>>>(Qb, Kb, Vt, AOb);
  gemm_out<<<dim3(256), dim3(256), 0, stream>>>(AOb, wob, bo, out);
}

// Round 6
// 196.103 us; speedup vs baseline: 1.5739x; 1.5739x over previous
//
#include <hip/hip_runtime.h>

// MultiHeadAttention: B=2, S=2048, H=1024, NH=16, HD=64
// Pipeline: [convert f32->f16] -> [fused QKV GEMM (V transposed, Q pre-scaled)]
//           -> [flash attention w/ LDS-staged double-buffered K,V] -> [output GEMM f32]

#define BD 2
#define SD 2048
#define HDIM 1024
#define NHD 16
#define HDD 64
#define NTOK 4096  // BD*SD
#define QSCALE 0.1803368801111204f  // (1/sqrt(64)) * log2(e), folded into Q

typedef float f32x4 __attribute__((ext_vector_type(4)));
typedef _Float16 f16x8 __attribute__((ext_vector_type(8)));
typedef _Float16 f16x4 __attribute__((ext_vector_type(4)));

__device__ __forceinline__ f32x4 mfma_f16(f16x8 a, f16x8 b, f32x4 c) {
  return __builtin_amdgcn_mfma_f32_16x16x32_f16(a, b, c, 0, 0, 0);
}

// ---------------- convert f32 -> f16 ----------------
// dst layout (f16 elems): [x 4M][wq 1M][wk 1M][wv 1M][wo 1M]
__global__ void convert_kernel(const float* __restrict__ x,
                               const float* __restrict__ wq, const float* __restrict__ wk,
                               const float* __restrict__ wv, const float* __restrict__ wo,
                               _Float16* __restrict__ dst) {
  const int total4 = (8 * 1024 * 1024) / 4;
  for (int idx = blockIdx.x * blockDim.x + threadIdx.x; idx < total4;
       idx += gridDim.x * blockDim.x) {
    int e = idx * 4;
    const float* s;
    if (e < 4 * 1024 * 1024) {
      s = x + e;
    } else {
      int w = (e - 4 * 1024 * 1024) >> 20;
      int off = e & 1048575;
      s = (w == 0 ? wq : w == 1 ? wk : w == 2 ? wv : wo) + off;
    }
    float4 v = *(const float4*)s;
    f16x4 h;
    h[0] = (_Float16)v.x; h[1] = (_Float16)v.y;
    h[2] = (_Float16)v.z; h[3] = (_Float16)v.w;
    *(f16x4*)(dst + e) = h;
  }
}

// ---------------- 128x128 GEMM mainloop (C = A * B^T form) ----------------
// C[i][j] = sum_k A[i][k] * B[j][k], K = 1024, BK = 32.
// 256 threads = 4 waves in 2x2; each wave 64x64 (4x4 MFMA 16x16x32 frags).
__device__ __forceinline__ void gemm_mainloop(
    const _Float16* __restrict__ Ap, const _Float16* __restrict__ Bp,
    int i0, int j0, _Float16* As, _Float16* Bs, f32x4 acc[4][4]) {
  const int tid = threadIdx.x;
  const int wid = tid >> 6, lane = tid & 63;
  const int lr = lane & 15, lg = lane >> 4;
  const int wm = wid >> 1, wn = wid & 1;
  const int srow = lane >> 2;
  const int scol = (lane & 3) * 8;

  for (int k0 = 0; k0 < HDIM; k0 += 32) {
#pragma unroll
    for (int it = 0; it < 2; ++it) {
      int rb = (wid * 2 + it) * 16;
      const _Float16* ga = Ap + (size_t)(i0 + rb + srow) * HDIM + k0 + scol;
      const _Float16* gb = Bp + (size_t)(j0 + rb + srow) * HDIM + k0 + scol;
      __builtin_amdgcn_global_load_lds(
          (__attribute__((address_space(1))) void*)ga,
          (__attribute__((address_space(3))) void*)(As + (wid * 2 + it) * 512), 16, 0, 0);
      __builtin_amdgcn_global_load_lds(
          (__attribute__((address_space(1))) void*)gb,
          (__attribute__((address_space(3))) void*)(Bs + (wid * 2 + it) * 512), 16, 0, 0);
    }
    __syncthreads();  // drains vmcnt: LDS data ready
    f16x8 af[4], bf[4];
#pragma unroll
    for (int mt = 0; mt < 4; mt++)
      af[mt] = *(const f16x8*)(As + (wm * 64 + mt * 16 + lr) * 32 + lg * 8);
#pragma unroll
    for (int nt = 0; nt < 4; nt++)
      bf[nt] = *(const f16x8*)(Bs + (wn * 64 + nt * 16 + lr) * 32 + lg * 8);
#pragma unroll
    for (int mt = 0; mt < 4; mt++)
#pragma unroll
      for (int nt = 0; nt < 4; nt++)
        acc[mt][nt] = mfma_f16(af[mt], bf[nt], acc[mt][nt]);
    __syncthreads();  // all reads done before next stage overwrites
  }
}

// ---------------- fused QKV projection ----------------
// blocks 0..255: Q = (x @ Wq^T + bq) * QSCALE  (softmax scale folded in)
// blocks 256..511: K = x @ Wk^T + bk
// blocks 512..767: V^T = Wv @ x^T  (output [bh][d][s], coalesced along s)
__global__ __launch_bounds__(256) void gemm_qkv(
    const _Float16* __restrict__ xb,
    const _Float16* __restrict__ wqb, const _Float16* __restrict__ wkb,
    const _Float16* __restrict__ wvb,
    const float* __restrict__ bq, const float* __restrict__ bk,
    const float* __restrict__ bv,
    _Float16* __restrict__ Qo, _Float16* __restrict__ Ko, _Float16* __restrict__ Vt) {
  __shared__ __attribute__((aligned(16))) _Float16 As[128 * 32];
  __shared__ __attribute__((aligned(16))) _Float16 Bs[128 * 32];
  const int bx = blockIdx.x;
  const int mat = bx >> 8;  // 0=Q, 1=K, 2=V
  const int sub = bx & 255;
  const _Float16 *Ap, *Bp;
  int i0, j0;
  if (mat < 2) {
    Ap = xb; Bp = (mat ? wkb : wqb);
    i0 = (sub >> 3) * 128;  // token tile
    j0 = (sub & 7) * 128;   // out-col tile
  } else {
    Ap = wvb; Bp = xb;
    i0 = (sub & 7) * 128;   // weight-row tile (h*64+d)
    j0 = (sub >> 3) * 128;  // token tile
  }
  f32x4 acc[4][4];
#pragma unroll
  for (int a = 0; a < 4; a++)
#pragma unroll
    for (int b = 0; b < 4; b++) acc[a][b] = (f32x4){0.f, 0.f, 0.f, 0.f};

  gemm_mainloop(Ap, Bp, i0, j0, As, Bs, acc);

  const int tid = threadIdx.x;
  const int wid = tid >> 6, lane = tid & 63;
  const int lr = lane & 15, lg = lane >> 4;
  const int wm = wid >> 1, wn = wid & 1;
  const float* bias = (mat == 0 ? bq : mat == 1 ? bk : bv);

#pragma unroll
  for (int mt = 0; mt < 4; mt++) {
#pragma unroll
    for (int nt = 0; nt < 4; nt++) {
      int i = i0 + wm * 64 + mt * 16 + 4 * lg;  // + r
      int j = j0 + wn * 64 + nt * 16 + lr;
      if (mat < 2) {
        float bj = bias[j];
        int h = j >> 6, d = j & 63;
        _Float16* dst = (mat ? Ko : Qo);
        float scl = (mat == 0) ? QSCALE : 1.0f;
#pragma unroll
        for (int r = 0; r < 4; r++) {
          int tok = i + r;
          int b = tok >> 11, s = tok & 2047;
          dst[(((size_t)(b * NHD + h)) * SD + s) * HDD + d] =
              (_Float16)((acc[mt][nt][r] + bj) * scl);
        }
      } else {
        int tok = j;
        int b = tok >> 11, s = tok & 2047;
#pragma unroll
        for (int r = 0; r < 4; r++) {
          int wr = i + r;  // weight row = h*64+d
          int h = wr >> 6, d = wr & 63;
          Vt[((size_t)(b * NHD + h) * HDD + d) * SD + s] =
              (_Float16)(acc[mt][nt][r] + bias[wr]);
        }
      }
    }
  }
}

// ---------------- output projection: out = attn @ Wo^T + bo (f32) ----------------
__global__ __launch_bounds__(256) void gemm_out(
    const _Float16* __restrict__ attn, const _Float16* __restrict__ wob,
    const float* __restrict__ bo, float* __restrict__ out) {
  __shared__ __attribute__((aligned(16))) _Float16 As[128 * 32];
  __shared__ __attribute__((aligned(16))) _Float16 Bs[128 * 32];
  const int sub = blockIdx.x;
  const int i0 = (sub >> 3) * 128, j0 = (sub & 7) * 128;
  f32x4 acc[4][4];
#pragma unroll
  for (int a = 0; a < 4; a++)
#pragma unroll
    for (int b = 0; b < 4; b++) acc[a][b] = (f32x4){0.f, 0.f, 0.f, 0.f};

  gemm_mainloop(attn, wob, i0, j0, As, Bs, acc);

  const int tid = threadIdx.x;
  const int wid = tid >> 6, lane = tid & 63;
  const int lr = lane & 15, lg = lane >> 4;
  const int wm = wid >> 1, wn = wid & 1;
#pragma unroll
  for (int mt = 0; mt < 4; mt++) {
#pragma unroll
    for (int nt = 0; nt < 4; nt++) {
      int i = i0 + wm * 64 + mt * 16 + 4 * lg;
      int j = j0 + wn * 64 + nt * 16 + lr;
      float bj = bo[j];
#pragma unroll
      for (int r = 0; r < 4; r++)
        out[(size_t)(i + r) * HDIM + j] = acc[mt][nt][r] + bj;
    }
  }
}

// ---------------- flash attention v2 ----------------
// grid (32 qblocks, 32 heads), 256 threads = 4 waves; each wave owns 16 q-rows.
// K,V staged cooperatively into double-buffered LDS (64B rows -> conflict-free
// ds_read_b128 fragments); next tile prefetched under current compute; ONE
// barrier per kv tile. P round-trips through wave-private LDS (no barrier).
__global__ __launch_bounds__(256) void attn_kernel(
    const _Float16* __restrict__ Q, const _Float16* __restrict__ K,
    const _Float16* __restrict__ VT, _Float16* __restrict__ AO) {
  const int bh = blockIdx.y, qb = blockIdx.x;
  const int tid = threadIdx.x, wv = tid >> 6, lane = tid & 63;
  const int lr = lane & 15, lg = lane >> 4;
  const int q0 = qb * 64 + wv * 16;
  const _Float16* Qh = Q + (size_t)bh * SD * HDD;
  const _Float16* Kh = K + (size_t)bh * SD * HDD;
  const _Float16* Vh = VT + (size_t)bh * HDD * SD;

  // 16KB + 16KB + 8KB = 40KB exactly -> 4 blocks/CU
  __shared__ __attribute__((aligned(16))) _Float16 Ks[2][2][64][32];  // [buf][kf][key][d-half]
  __shared__ __attribute__((aligned(16))) _Float16 Vs[2][2][64][32];  // [buf][kf][d][key-half]
  __shared__ __attribute__((aligned(16))) _Float16 P_lds[4][16][64];

  const int grow = lane >> 2;       // row within 16-row staging chunk
  const int gcol = (lane & 3) * 8;  // f16-elem col offset (4 lanes x 16B = 64B row)

  // stage K,V tile starting at key kv0 into buffer b (4 gload_lds per wave)
  auto stage = [&](int b, int kv0) {
#pragma unroll
    for (int kf = 0; kf < 2; kf++) {
      const _Float16* gk = Kh + (size_t)(kv0 + wv * 16 + grow) * HDD + kf * 32 + gcol;
      __builtin_amdgcn_global_load_lds(
          (__attribute__((address_space(1))) void*)gk,
          (__attribute__((address_space(3))) void*)(&Ks[b][kf][wv * 16][0]), 16, 0, 0);
      const _Float16* gv = Vh + (size_t)(wv * 16 + grow) * SD + kv0 + kf * 32 + gcol;
      __builtin_amdgcn_global_load_lds(
          (__attribute__((address_space(1))) void*)gv,
          (__attribute__((address_space(3))) void*)(&Vs[b][kf][wv * 16][0]), 16, 0, 0);
    }
  };

  // Q fragments (Q is pre-scaled by QSCALE at projection time)
  f16x8 qf[2];
#pragma unroll
  for (int kf = 0; kf < 2; kf++)
    qf[kf] = *(const f16x8*)(Qh + (size_t)(q0 + lr) * HDD + kf * 32 + lg * 8);

  f32x4 acc[4];
  float mrun[4], lsum[4];
#pragma unroll
  for (int i = 0; i < 4; i++) {
    acc[i] = (f32x4){0.f, 0.f, 0.f, 0.f};
    mrun[i] = -1e30f;
    lsum[i] = 0.f;
  }

  stage(0, 0);
  __syncthreads();  // implicit vmcnt(0) drain -> buffer 0 ready
  int cur = 0;

  for (int t = 0; t < SD / 64; ++t) {
    if (t + 1 < SD / 64) stage(cur ^ 1, (t + 1) * 64);  // prefetch under compute

    // ---- S = Q K^T (rows=q, cols=key); sc already in log2-units ----
    f32x4 sc[4];
#pragma unroll
    for (int nt = 0; nt < 4; nt++) sc[nt] = (f32x4){0.f, 0.f, 0.f, 0.f};
#pragma unroll
    for (int nt = 0; nt < 4; nt++) {
#pragma unroll
      for (int kf = 0; kf < 2; kf++) {
        f16x8 kfr = *(const f16x8*)&Ks[cur][kf][nt * 16 + lr][lg * 8];
        sc[nt] = mfma_f16(qf[kf], kfr, sc[nt]);
      }
    }
    // ---- online softmax (row = 4*lg + r, col = nt*16 + lr) ----
    float tmax[4];
#pragma unroll
    for (int r = 0; r < 4; r++)
      tmax[r] = fmaxf(fmaxf(sc[0][r], sc[1][r]), fmaxf(sc[2][r], sc[3][r]));
#pragma unroll
    for (int off = 1; off < 16; off <<= 1)
#pragma unroll
      for (int r = 0; r < 4; r++) tmax[r] = fmaxf(tmax[r], __shfl_xor(tmax[r], off));
    float fmul[4], rs[4];
#pragma unroll
    for (int r = 0; r < 4; r++) {
      float mn = fmaxf(mrun[r], tmax[r]);
      fmul[r] = exp2f(mrun[r] - mn);
      mrun[r] = mn;
      rs[r] = 0.f;
    }
    float p[4][4];
#pragma unroll
    for (int nt = 0; nt < 4; nt++)
#pragma unroll
      for (int r = 0; r < 4; r++) {
        p[nt][r] = exp2f(sc[nt][r] - mrun[r]);
        rs[r] += p[nt][r];
      }
#pragma unroll
    for (int off = 1; off < 16; off <<= 1)
#pragma unroll
      for (int r = 0; r < 4; r++) rs[r] += __shfl_xor(rs[r], off);
#pragma unroll
    for (int r = 0; r < 4; r++) lsum[r] = lsum[r] * fmul[r] + rs[r];
#pragma unroll
    for (int ntd = 0; ntd < 4; ntd++)
#pragma unroll
      for (int r = 0; r < 4; r++) acc[ntd][r] *= fmul[r];
    // ---- stage P (wave-private region, no barrier needed) ----
#pragma unroll
    for (int nt = 0; nt < 4; nt++)
#pragma unroll
      for (int r = 0; r < 4; r++)
        P_lds[wv][lg * 4 + r][nt * 16 + lr] = (_Float16)p[nt][r];
    // ---- O += P V ----
#pragma unroll
    for (int kf = 0; kf < 2; kf++) {
      f16x8 pf = *(const f16x8*)&P_lds[wv][lr][kf * 32 + lg * 8];
#pragma unroll
      for (int ntd = 0; ntd < 4; ntd++) {
        f16x8 vf = *(const f16x8*)&Vs[cur][kf][ntd * 16 + lr][lg * 8];
        acc[ntd] = mfma_f16(pf, vf, acc[ntd]);
      }
    }
    __syncthreads();  // drains vmcnt (next buffer staged) + all reads of cur done
    cur ^= 1;
  }
  // ---- epilogue: normalize, write attn output [token][H] as f16 ----
  const int b = bh >> 4, h = bh & 15;
#pragma unroll
  for (int r = 0; r < 4; r++) {
    float inv = 1.0f / lsum[r];
    int srow = q0 + lg * 4 + r;
#pragma unroll
    for (int ntd = 0; ntd < 4; ntd++) {
      int col = h * 64 + ntd * 16 + lr;
      AO[((size_t)(b * SD + srow)) * HDIM + col] = (_Float16)(acc[ntd][r] * inv);
    }
  }
}

extern "C" void kernel_launch(void* const* d_in, const int* in_sizes, int n_in,
                              void* d_out, int out_size, void* d_ws, size_t ws_size,
                              hipStream_t stream) {
  const float* x  = (const float*)d_in[0];
  const float* Wq = (const float*)d_in[1];
  const float* bq = (const float*)d_in[2];
  const float* Wk = (const float*)d_in[3];
  const float* bk = (const float*)d_in[4];
  const float* Wv = (const float*)d_in[5];
  const float* bv = (const float*)d_in[6];
  const float* Wo = (const float*)d_in[7];
  const float* bo = (const float*)d_in[8];
  float* out = (float*)d_out;

  _Float16* xb  = (_Float16*)d_ws;            // 4M
  _Float16* wqb = xb + 4 * 1024 * 1024;       // 1M
  _Float16* wkb = wqb + 1024 * 1024;
  _Float16* wvb = wkb + 1024 * 1024;
  _Float16* wob = wvb + 1024 * 1024;
  _Float16* Qb  = wob + 1024 * 1024;          // 4M  [bh][s][d]  (pre-scaled)
  _Float16* Kb  = Qb + 4 * 1024 * 1024;       // 4M  [bh][s][d]
  _Float16* Vt  = Kb + 4 * 1024 * 1024;       // 4M  [bh][d][s]
  _Float16* AOb = Vt + 4 * 1024 * 1024;       // 4M  [token][H]

  convert_kernel<<<dim3(1024), dim3(256), 0, stream>>>(x, Wq, Wk, Wv, Wo, xb);
  gemm_qkv<<<dim3(768), dim3(256), 0, stream>>>(xb, wqb, wkb, wvb, bq, bk, bv, Qb, Kb, Vt);
  attn_kernel<<<dim3(32, 32), dim3(256), 0, stream>>>(Qb, Kb, Vt, AOb);
  gemm_out<<<dim3(256), dim3(256), 0, stream>>>(AOb, wob, bo, out);
}

// Round 7
// 183.186 us; speedup vs baseline: 1.6849x; 1.0705x over previous
//
#include <hip/hip_runtime.h>

// MultiHeadAttention: B=2, S=2048, H=1024, NH=16, HD=64
// Pipeline: [convert f32->f16] -> [fused QKV GEMM (V transposed, Q pre-scaled)]
//           -> [flash attention, swizzled LDS K/V/P + defer-max] -> [output GEMM f32]

#define BD 2
#define SD 2048
#define HDIM 1024
#define NHD 16
#define HDD 64
#define NTOK 4096  // BD*SD
#define QSCALE 0.1803368801111204f  // (1/sqrt(64)) * log2(e), folded into Q

typedef float f32x4 __attribute__((ext_vector_type(4)));
typedef _Float16 f16x8 __attribute__((ext_vector_type(8)));
typedef _Float16 f16x4 __attribute__((ext_vector_type(4)));

__device__ __forceinline__ f32x4 mfma_f16(f16x8 a, f16x8 b, f32x4 c) {
  return __builtin_amdgcn_mfma_f32_16x16x32_f16(a, b, c, 0, 0, 0);
}

// ---------------- convert f32 -> f16 ----------------
// dst layout (f16 elems): [x 4M][wq 1M][wk 1M][wv 1M][wo 1M]
__global__ void convert_kernel(const float* __restrict__ x,
                               const float* __restrict__ wq, const float* __restrict__ wk,
                               const float* __restrict__ wv, const float* __restrict__ wo,
                               _Float16* __restrict__ dst) {
  const int total4 = (8 * 1024 * 1024) / 4;
  for (int idx = blockIdx.x * blockDim.x + threadIdx.x; idx < total4;
       idx += gridDim.x * blockDim.x) {
    int e = idx * 4;
    const float* s;
    if (e < 4 * 1024 * 1024) {
      s = x + e;
    } else {
      int w = (e - 4 * 1024 * 1024) >> 20;
      int off = e & 1048575;
      s = (w == 0 ? wq : w == 1 ? wk : w == 2 ? wv : wo) + off;
    }
    float4 v = *(const float4*)s;
    f16x4 h;
    h[0] = (_Float16)v.x; h[1] = (_Float16)v.y;
    h[2] = (_Float16)v.z; h[3] = (_Float16)v.w;
    *(f16x4*)(dst + e) = h;
  }
}

// ---------------- 128x128 GEMM mainloop (C = A * B^T form) ----------------
__device__ __forceinline__ void gemm_mainloop(
    const _Float16* __restrict__ Ap, const _Float16* __restrict__ Bp,
    int i0, int j0, _Float16* As, _Float16* Bs, f32x4 acc[4][4]) {
  const int tid = threadIdx.x;
  const int wid = tid >> 6, lane = tid & 63;
  const int lr = lane & 15, lg = lane >> 4;
  const int wm = wid >> 1, wn = wid & 1;
  const int srow = lane >> 2;
  const int scol = (lane & 3) * 8;

  for (int k0 = 0; k0 < HDIM; k0 += 32) {
#pragma unroll
    for (int it = 0; it < 2; ++it) {
      int rb = (wid * 2 + it) * 16;
      const _Float16* ga = Ap + (size_t)(i0 + rb + srow) * HDIM + k0 + scol;
      const _Float16* gb = Bp + (size_t)(j0 + rb + srow) * HDIM + k0 + scol;
      __builtin_amdgcn_global_load_lds(
          (__attribute__((address_space(1))) void*)ga,
          (__attribute__((address_space(3))) void*)(As + (wid * 2 + it) * 512), 16, 0, 0);
      __builtin_amdgcn_global_load_lds(
          (__attribute__((address_space(1))) void*)gb,
          (__attribute__((address_space(3))) void*)(Bs + (wid * 2 + it) * 512), 16, 0, 0);
    }
    __syncthreads();
    f16x8 af[4], bf[4];
#pragma unroll
    for (int mt = 0; mt < 4; mt++)
      af[mt] = *(const f16x8*)(As + (wm * 64 + mt * 16 + lr) * 32 + lg * 8);
#pragma unroll
    for (int nt = 0; nt < 4; nt++)
      bf[nt] = *(const f16x8*)(Bs + (wn * 64 + nt * 16 + lr) * 32 + lg * 8);
#pragma unroll
    for (int mt = 0; mt < 4; mt++)
#pragma unroll
      for (int nt = 0; nt < 4; nt++)
        acc[mt][nt] = mfma_f16(af[mt], bf[nt], acc[mt][nt]);
    __syncthreads();
  }
}

// ---------------- fused QKV projection ----------------
__global__ __launch_bounds__(256) void gemm_qkv(
    const _Float16* __restrict__ xb,
    const _Float16* __restrict__ wqb, const _Float16* __restrict__ wkb,
    const _Float16* __restrict__ wvb,
    const float* __restrict__ bq, const float* __restrict__ bk,
    const float* __restrict__ bv,
    _Float16* __restrict__ Qo, _Float16* __restrict__ Ko, _Float16* __restrict__ Vt) {
  __shared__ __attribute__((aligned(16))) _Float16 As[128 * 32];
  __shared__ __attribute__((aligned(16))) _Float16 Bs[128 * 32];
  const int bx = blockIdx.x;
  const int mat = bx >> 8;  // 0=Q, 1=K, 2=V
  const int sub = bx & 255;
  const _Float16 *Ap, *Bp;
  int i0, j0;
  if (mat < 2) {
    Ap = xb; Bp = (mat ? wkb : wqb);
    i0 = (sub >> 3) * 128;
    j0 = (sub & 7) * 128;
  } else {
    Ap = wvb; Bp = xb;
    i0 = (sub & 7) * 128;
    j0 = (sub >> 3) * 128;
  }
  f32x4 acc[4][4];
#pragma unroll
  for (int a = 0; a < 4; a++)
#pragma unroll
    for (int b = 0; b < 4; b++) acc[a][b] = (f32x4){0.f, 0.f, 0.f, 0.f};

  gemm_mainloop(Ap, Bp, i0, j0, As, Bs, acc);

  const int tid = threadIdx.x;
  const int wid = tid >> 6, lane = tid & 63;
  const int lr = lane & 15, lg = lane >> 4;
  const int wm = wid >> 1, wn = wid & 1;
  const float* bias = (mat == 0 ? bq : mat == 1 ? bk : bv);

#pragma unroll
  for (int mt = 0; mt < 4; mt++) {
#pragma unroll
    for (int nt = 0; nt < 4; nt++) {
      int i = i0 + wm * 64 + mt * 16 + 4 * lg;
      int j = j0 + wn * 64 + nt * 16 + lr;
      if (mat < 2) {
        float bj = bias[j];
        int h = j >> 6, d = j & 63;
        _Float16* dst = (mat ? Ko : Qo);
        float scl = (mat == 0) ? QSCALE : 1.0f;
#pragma unroll
        for (int r = 0; r < 4; r++) {
          int tok = i + r;
          int b = tok >> 11, s = tok & 2047;
          dst[(((size_t)(b * NHD + h)) * SD + s) * HDD + d] =
              (_Float16)((acc[mt][nt][r] + bj) * scl);
        }
      } else {
        int tok = j;
        int b = tok >> 11, s = tok & 2047;
#pragma unroll
        for (int r = 0; r < 4; r++) {
          int wr = i + r;
          int h = wr >> 6, d = wr & 63;
          Vt[((size_t)(b * NHD + h) * HDD + d) * SD + s] =
              (_Float16)(acc[mt][nt][r] + bias[wr]);
        }
      }
    }
  }
}

// ---------------- output projection: out = attn @ Wo^T + bo (f32) ----------------
__global__ __launch_bounds__(256) void gemm_out(
    const _Float16* __restrict__ attn, const _Float16* __restrict__ wob,
    const float* __restrict__ bo, float* __restrict__ out) {
  __shared__ __attribute__((aligned(16))) _Float16 As[128 * 32];
  __shared__ __attribute__((aligned(16))) _Float16 Bs[128 * 32];
  const int sub = blockIdx.x;
  const int i0 = (sub >> 3) * 128, j0 = (sub & 7) * 128;
  f32x4 acc[4][4];
#pragma unroll
  for (int a = 0; a < 4; a++)
#pragma unroll
    for (int b = 0; b < 4; b++) acc[a][b] = (f32x4){0.f, 0.f, 0.f, 0.f};

  gemm_mainloop(attn, wob, i0, j0, As, Bs, acc);

  const int tid = threadIdx.x;
  const int wid = tid >> 6, lane = tid & 63;
  const int lr = lane & 15, lg = lane >> 4;
  const int wm = wid >> 1, wn = wid & 1;
#pragma unroll
  for (int mt = 0; mt < 4; mt++) {
#pragma unroll
    for (int nt = 0; nt < 4; nt++) {
      int i = i0 + wm * 64 + mt * 16 + 4 * lg;
      int j = j0 + wn * 64 + nt * 16 + lr;
      float bj = bo[j];
#pragma unroll
      for (int r = 0; r < 4; r++)
        out[(size_t)(i + r) * HDIM + j] = acc[mt][nt][r] + bj;
    }
  }
}

// ---------------- flash attention v3 ----------------
// Swizzles:
//  K/V tiles (row stride 64B = 4 slots of 16B): physical slot = logical ^ ((row>>1)&3).
//    global_load_lds writes LDS linearly, so the permutation is applied to the
//    per-lane GLOBAL source column (rule: linear dest + inverse-swz source + swz read).
//  P tile (row stride 128B = 8 slots): physical slot = logical ^ (((row>>2)&3)<<1).
//    Chosen so BOTH the write pattern (row=lg*4+r) and read pattern (row=lr)
//    spread uniformly over all 8 slots / 32 banks.
//  Defer-max (T13, THR=8): skip acc/lsum rescale while max grows < 8 (log2 units).
__global__ __launch_bounds__(256) void attn_kernel(
    const _Float16* __restrict__ Q, const _Float16* __restrict__ K,
    const _Float16* __restrict__ VT, _Float16* __restrict__ AO) {
  const int bh = blockIdx.y, qb = blockIdx.x;
  const int tid = threadIdx.x, wv = tid >> 6, lane = tid & 63;
  const int lr = lane & 15, lg = lane >> 4;
  const int q0 = qb * 64 + wv * 16;
  const _Float16* Qh = Q + (size_t)bh * SD * HDD;
  const _Float16* Kh = K + (size_t)bh * SD * HDD;
  const _Float16* Vh = VT + (size_t)bh * HDD * SD;

  // 16KB + 16KB + 8KB = 40KB
  __shared__ __attribute__((aligned(16))) _Float16 Ks[2][2][64][32];  // [buf][kf][key][d-half]
  __shared__ __attribute__((aligned(16))) _Float16 Vs[2][2][64][32];  // [buf][kf][d][key-half]
  __shared__ __attribute__((aligned(16))) _Float16 P_lds[4][16][64];

  const int grow = lane >> 2;  // row within 16-row staging chunk
  // pre-swizzled source slot: (lane&3) ^ K_KV(row) where K_KV(row)=(row>>1)&3 = (lane>>3)&3
  const int gswz = (((lane & 3) ^ ((lane >> 3) & 3)) * 8);

  auto stage = [&](int b, int kv0) {
#pragma unroll
    for (int kf = 0; kf < 2; kf++) {
      const _Float16* gk = Kh + (size_t)(kv0 + wv * 16 + grow) * HDD + kf * 32 + gswz;
      __builtin_amdgcn_global_load_lds(
          (__attribute__((address_space(1))) void*)gk,
          (__attribute__((address_space(3))) void*)(&Ks[b][kf][wv * 16][0]), 16, 0, 0);
      const _Float16* gv = Vh + (size_t)(wv * 16 + grow) * SD + kv0 + kf * 32 + gswz;
      __builtin_amdgcn_global_load_lds(
          (__attribute__((address_space(1))) void*)gv,
          (__attribute__((address_space(3))) void*)(&Vs[b][kf][wv * 16][0]), 16, 0, 0);
    }
  };

  // fragment-read swizzled column (row = nt*16+lr): (lg ^ ((lr>>1)&3)) * 8
  const int fswz = (lg ^ ((lr >> 1) & 3)) * 8;
  // P write slot XOR key: K_P(row)= ((row>>2)&3)<<1; write rows lg*4+r -> key = lg<<1
  const int pwkey = lg << 1;
  // P read (row = lr): key = ((lr>>2)&3)<<1
  const int prkey = ((lr >> 2) & 3) << 1;

  // Q fragments (pre-scaled by QSCALE)
  f16x8 qf[2];
#pragma unroll
  for (int kf = 0; kf < 2; kf++)
    qf[kf] = *(const f16x8*)(Qh + (size_t)(q0 + lr) * HDD + kf * 32 + lg * 8);

  f32x4 acc[4];
  float mrun[4], lsum[4];
#pragma unroll
  for (int i = 0; i < 4; i++) {
    acc[i] = (f32x4){0.f, 0.f, 0.f, 0.f};
    mrun[i] = -1e30f;
    lsum[i] = 0.f;
  }

  stage(0, 0);
  __syncthreads();
  int cur = 0;

  for (int t = 0; t < SD / 64; ++t) {
    if (t + 1 < SD / 64) stage(cur ^ 1, (t + 1) * 64);  // prefetch under compute

    // ---- S = Q K^T (rows=q, cols=key); values already in log2 units ----
    f32x4 sc[4];
#pragma unroll
    for (int nt = 0; nt < 4; nt++) sc[nt] = (f32x4){0.f, 0.f, 0.f, 0.f};
#pragma unroll
    for (int nt = 0; nt < 4; nt++) {
#pragma unroll
      for (int kf = 0; kf < 2; kf++) {
        f16x8 kfr = *(const f16x8*)&Ks[cur][kf][nt * 16 + lr][fswz];
        sc[nt] = mfma_f16(qf[kf], kfr, sc[nt]);
      }
    }
    // ---- online softmax (row = 4*lg + r, col = nt*16 + lr) ----
    float tmax[4];
#pragma unroll
    for (int r = 0; r < 4; r++)
      tmax[r] = fmaxf(fmaxf(sc[0][r], sc[1][r]), fmaxf(sc[2][r], sc[3][r]));
#pragma unroll
    for (int off = 1; off < 16; off <<= 1)
#pragma unroll
      for (int r = 0; r < 4; r++) tmax[r] = fmaxf(tmax[r], __shfl_xor(tmax[r], off));

    // defer-max: rescale only when some row's max grew by > 8 (log2 units)
    float need = fmaxf(fmaxf(tmax[0] - mrun[0], tmax[1] - mrun[1]),
                       fmaxf(tmax[2] - mrun[2], tmax[3] - mrun[3]));
    if (__any(need > 8.0f)) {
#pragma unroll
      for (int r = 0; r < 4; r++) {
        float mn = fmaxf(mrun[r], tmax[r]);
        float fm = exp2f(mrun[r] - mn);
        mrun[r] = mn;
        lsum[r] *= fm;
#pragma unroll
        for (int ntd = 0; ntd < 4; ntd++) acc[ntd][r] *= fm;
      }
    }

    float p[4][4], rs[4];
#pragma unroll
    for (int r = 0; r < 4; r++) rs[r] = 0.f;
#pragma unroll
    for (int nt = 0; nt < 4; nt++)
#pragma unroll
      for (int r = 0; r < 4; r++) {
        p[nt][r] = exp2f(sc[nt][r] - mrun[r]);
        rs[r] += p[nt][r];
      }
#pragma unroll
    for (int off = 1; off < 16; off <<= 1)
#pragma unroll
      for (int r = 0; r < 4; r++) rs[r] += __shfl_xor(rs[r], off);
#pragma unroll
    for (int r = 0; r < 4; r++) lsum[r] += rs[r];

    // ---- stage P (wave-private, swizzled, no barrier) ----
#pragma unroll
    for (int nt = 0; nt < 4; nt++)
#pragma unroll
      for (int r = 0; r < 4; r++) {
        int pslot = ((nt * 2 + (lr >> 3)) ^ pwkey);
        P_lds[wv][lg * 4 + r][pslot * 8 + (lr & 7)] = (_Float16)p[nt][r];
      }
    // ---- O += P V ----
#pragma unroll
    for (int kf = 0; kf < 2; kf++) {
      f16x8 pf = *(const f16x8*)&P_lds[wv][lr][((kf * 4 + lg) ^ prkey) * 8];
#pragma unroll
      for (int ntd = 0; ntd < 4; ntd++) {
        f16x8 vf = *(const f16x8*)&Vs[cur][kf][ntd * 16 + lr][fswz];
        acc[ntd] = mfma_f16(pf, vf, acc[ntd]);
      }
    }
    __syncthreads();  // drains vmcnt (next buffer staged) + all reads of cur done
    cur ^= 1;
  }
  // ---- epilogue: normalize, write attn output [token][H] as f16 ----
  const int b = bh >> 4, h = bh & 15;
#pragma unroll
  for (int r = 0; r < 4; r++) {
    float inv = 1.0f / lsum[r];
    int srow = q0 + lg * 4 + r;
#pragma unroll
    for (int ntd = 0; ntd < 4; ntd++) {
      int col = h * 64 + ntd * 16 + lr;
      AO[((size_t)(b * SD + srow)) * HDIM + col] = (_Float16)(acc[ntd][r] * inv);
    }
  }
}

extern "C" void kernel_launch(void* const* d_in, const int* in_sizes, int n_in,
                              void* d_out, int out_size, void* d_ws, size_t ws_size,
                              hipStream_t stream) {
  const float* x  = (const float*)d_in[0];
  const float* Wq = (const float*)d_in[1];
  const float* bq = (const float*)d_in[2];
  const float* Wk = (const float*)d_in[3];
  const float* bk = (const float*)d_in[4];
  const float* Wv = (const float*)d_in[5];
  const float* bv = (const float*)d_in[6];
  const float* Wo = (const float*)d_in[7];
  const float* bo = (const float*)d_in[8];
  float* out = (float*)d_out;

  _Float16* xb  = (_Float16*)d_ws;            // 4M
  _Float16* wqb = xb + 4 * 1024 * 1024;       // 1M
  _Float16* wkb = wqb + 1024 * 1024;
  _Float16* wvb = wkb + 1024 * 1024;
  _Float16* wob = wvb + 1024 * 1024;
  _Float16* Qb  = wob + 1024 * 1024;          // 4M  [bh][s][d]  (pre-scaled)
  _Float16* Kb  = Qb + 4 * 1024 * 1024;       // 4M  [bh][s][d]
  _Float16* Vt  = Kb + 4 * 1024 * 1024;       // 4M  [bh][d][s]
  _Float16* AOb = Vt + 4 * 1024 * 1024;       // 4M  [token][H]

  convert_kernel<<<dim3(1024), dim3(256), 0, stream>>>(x, Wq, Wk, Wv, Wo, xb);
  gemm_qkv<<<dim3(768), dim3(256), 0, stream>>>(xb, wqb, wkb, wvb, bq, bk, bv, Qb, Kb, Vt);
  attn_kernel<<<dim3(32, 32), dim3(256), 0, stream>>>(Qb, Kb, Vt, AOb);
  gemm_out<<<dim3(256), dim3(256), 0, stream>>>(AOb, wob, bo, out);
}

// Round 8
// 169.721 us; speedup vs baseline: 1.8185x; 1.0793x over previous
//
#include <hip/hip_runtime.h>

// MultiHeadAttention: B=2, S=2048, H=1024, NH=16, HD=64
// Pipeline: [convert f32->f16] -> [fused QKV GEMM (V transposed, Q pre-scaled)]
//           -> [flash attention: swizzled LDS K/V/P, counted-vmcnt K/V pipeline,
//               deferred sum-reduce, defer-max] -> [output GEMM f32]

#define BD 2
#define SD 2048
#define HDIM 1024
#define NHD 16
#define HDD 64
#define NTOK 4096  // BD*SD
#define QSCALE 0.1803368801111204f  // (1/sqrt(64)) * log2(e), folded into Q

typedef float f32x4 __attribute__((ext_vector_type(4)));
typedef _Float16 f16x8 __attribute__((ext_vector_type(8)));
typedef _Float16 f16x4 __attribute__((ext_vector_type(4)));

__device__ __forceinline__ f32x4 mfma_f16(f16x8 a, f16x8 b, f32x4 c) {
  return __builtin_amdgcn_mfma_f32_16x16x32_f16(a, b, c, 0, 0, 0);
}

// ---------------- convert f32 -> f16 ----------------
__global__ void convert_kernel(const float* __restrict__ x,
                               const float* __restrict__ wq, const float* __restrict__ wk,
                               const float* __restrict__ wv, const float* __restrict__ wo,
                               _Float16* __restrict__ dst) {
  const int total4 = (8 * 1024 * 1024) / 4;
  for (int idx = blockIdx.x * blockDim.x + threadIdx.x; idx < total4;
       idx += gridDim.x * blockDim.x) {
    int e = idx * 4;
    const float* s;
    if (e < 4 * 1024 * 1024) {
      s = x + e;
    } else {
      int w = (e - 4 * 1024 * 1024) >> 20;
      int off = e & 1048575;
      s = (w == 0 ? wq : w == 1 ? wk : w == 2 ? wv : wo) + off;
    }
    float4 v = *(const float4*)s;
    f16x4 h;
    h[0] = (_Float16)v.x; h[1] = (_Float16)v.y;
    h[2] = (_Float16)v.z; h[3] = (_Float16)v.w;
    *(f16x4*)(dst + e) = h;
  }
}

// ---------------- 128x128 GEMM mainloop (C = A * B^T form) ----------------
__device__ __forceinline__ void gemm_mainloop(
    const _Float16* __restrict__ Ap, const _Float16* __restrict__ Bp,
    int i0, int j0, _Float16* As, _Float16* Bs, f32x4 acc[4][4]) {
  const int tid = threadIdx.x;
  const int wid = tid >> 6, lane = tid & 63;
  const int lr = lane & 15, lg = lane >> 4;
  const int wm = wid >> 1, wn = wid & 1;
  const int srow = lane >> 2;
  const int scol = (lane & 3) * 8;

  for (int k0 = 0; k0 < HDIM; k0 += 32) {
#pragma unroll
    for (int it = 0; it < 2; ++it) {
      int rb = (wid * 2 + it) * 16;
      const _Float16* ga = Ap + (size_t)(i0 + rb + srow) * HDIM + k0 + scol;
      const _Float16* gb = Bp + (size_t)(j0 + rb + srow) * HDIM + k0 + scol;
      __builtin_amdgcn_global_load_lds(
          (__attribute__((address_space(1))) void*)ga,
          (__attribute__((address_space(3))) void*)(As + (wid * 2 + it) * 512), 16, 0, 0);
      __builtin_amdgcn_global_load_lds(
          (__attribute__((address_space(1))) void*)gb,
          (__attribute__((address_space(3))) void*)(Bs + (wid * 2 + it) * 512), 16, 0, 0);
    }
    __syncthreads();
    f16x8 af[4], bf[4];
#pragma unroll
    for (int mt = 0; mt < 4; mt++)
      af[mt] = *(const f16x8*)(As + (wm * 64 + mt * 16 + lr) * 32 + lg * 8);
#pragma unroll
    for (int nt = 0; nt < 4; nt++)
      bf[nt] = *(const f16x8*)(Bs + (wn * 64 + nt * 16 + lr) * 32 + lg * 8);
#pragma unroll
    for (int mt = 0; mt < 4; mt++)
#pragma unroll
      for (int nt = 0; nt < 4; nt++)
        acc[mt][nt] = mfma_f16(af[mt], bf[nt], acc[mt][nt]);
    __syncthreads();
  }
}

// ---------------- fused QKV projection ----------------
__global__ __launch_bounds__(256) void gemm_qkv(
    const _Float16* __restrict__ xb,
    const _Float16* __restrict__ wqb, const _Float16* __restrict__ wkb,
    const _Float16* __restrict__ wvb,
    const float* __restrict__ bq, const float* __restrict__ bk,
    const float* __restrict__ bv,
    _Float16* __restrict__ Qo, _Float16* __restrict__ Ko, _Float16* __restrict__ Vt) {
  __shared__ __attribute__((aligned(16))) _Float16 As[128 * 32];
  __shared__ __attribute__((aligned(16))) _Float16 Bs[128 * 32];
  const int bx = blockIdx.x;
  const int mat = bx >> 8;  // 0=Q, 1=K, 2=V
  const int sub = bx & 255;
  const _Float16 *Ap, *Bp;
  int i0, j0;
  if (mat < 2) {
    Ap = xb; Bp = (mat ? wkb : wqb);
    i0 = (sub >> 3) * 128;
    j0 = (sub & 7) * 128;
  } else {
    Ap = wvb; Bp = xb;
    i0 = (sub & 7) * 128;
    j0 = (sub >> 3) * 128;
  }
  f32x4 acc[4][4];
#pragma unroll
  for (int a = 0; a < 4; a++)
#pragma unroll
    for (int b = 0; b < 4; b++) acc[a][b] = (f32x4){0.f, 0.f, 0.f, 0.f};

  gemm_mainloop(Ap, Bp, i0, j0, As, Bs, acc);

  const int tid = threadIdx.x;
  const int wid = tid >> 6, lane = tid & 63;
  const int lr = lane & 15, lg = lane >> 4;
  const int wm = wid >> 1, wn = wid & 1;
  const float* bias = (mat == 0 ? bq : mat == 1 ? bk : bv);

#pragma unroll
  for (int mt = 0; mt < 4; mt++) {
#pragma unroll
    for (int nt = 0; nt < 4; nt++) {
      int i = i0 + wm * 64 + mt * 16 + 4 * lg;
      int j = j0 + wn * 64 + nt * 16 + lr;
      if (mat < 2) {
        float bj = bias[j];
        int h = j >> 6, d = j & 63;
        _Float16* dst = (mat ? Ko : Qo);
        float scl = (mat == 0) ? QSCALE : 1.0f;
#pragma unroll
        for (int r = 0; r < 4; r++) {
          int tok = i + r;
          int b = tok >> 11, s = tok & 2047;
          dst[(((size_t)(b * NHD + h)) * SD + s) * HDD + d] =
              (_Float16)((acc[mt][nt][r] + bj) * scl);
        }
      } else {
        int tok = j;
        int b = tok >> 11, s = tok & 2047;
#pragma unroll
        for (int r = 0; r < 4; r++) {
          int wr = i + r;
          int h = wr >> 6, d = wr & 63;
          Vt[((size_t)(b * NHD + h) * HDD + d) * SD + s] =
              (_Float16)(acc[mt][nt][r] + bias[wr]);
        }
      }
    }
  }
}

// ---------------- output projection: out = attn @ Wo^T + bo (f32) ----------------
__global__ __launch_bounds__(256) void gemm_out(
    const _Float16* __restrict__ attn, const _Float16* __restrict__ wob,
    const float* __restrict__ bo, float* __restrict__ out) {
  __shared__ __attribute__((aligned(16))) _Float16 As[128 * 32];
  __shared__ __attribute__((aligned(16))) _Float16 Bs[128 * 32];
  const int sub = blockIdx.x;
  const int i0 = (sub >> 3) * 128, j0 = (sub & 7) * 128;
  f32x4 acc[4][4];
#pragma unroll
  for (int a = 0; a < 4; a++)
#pragma unroll
    for (int b = 0; b < 4; b++) acc[a][b] = (f32x4){0.f, 0.f, 0.f, 0.f};

  gemm_mainloop(attn, wob, i0, j0, As, Bs, acc);

  const int tid = threadIdx.x;
  const int wid = tid >> 6, lane = tid & 63;
  const int lr = lane & 15, lg = lane >> 4;
  const int wm = wid >> 1, wn = wid & 1;
#pragma unroll
  for (int mt = 0; mt < 4; mt++) {
#pragma unroll
    for (int nt = 0; nt < 4; nt++) {
      int i = i0 + wm * 64 + mt * 16 + 4 * lg;
      int j = j0 + wn * 64 + nt * 16 + lr;
      float bj = bo[j];
#pragma unroll
      for (int r = 0; r < 4; r++)
        out[(size_t)(i + r) * HDIM + j] = acc[mt][nt][r] + bj;
    }
  }
}

// ---------------- flash attention v4 ----------------
// Counted-vmcnt software pipeline (T3/T4):
//   per tile, per wave: [wait vmcnt(2): K(t) done] [s_barrier] [issue K(t+1)]
//   [QK^T + softmax] [wait vmcnt(2): V(t) done] [issue V(t+1)] [P stage + PV].
//   Issue->use distance = one full tile for both K and V; vmcnt never 0.
//   Last tile issues modulo-wrapped dummy loads to keep counts uniform.
// Softmax: per-lane partial lsum (cross-lane sum deferred to epilogue; rescale
//   factors are row-uniform so partials stay exact); max3-fused tmax tree;
//   defer-max (THR=8).
__global__ __launch_bounds__(256) void attn_kernel(
    const _Float16* __restrict__ Q, const _Float16* __restrict__ K,
    const _Float16* __restrict__ VT, _Float16* __restrict__ AO) {
  const int bh = blockIdx.y, qb = blockIdx.x;
  const int tid = threadIdx.x, wv = tid >> 6, lane = tid & 63;
  const int lr = lane & 15, lg = lane >> 4;
  const int q0 = qb * 64 + wv * 16;
  const _Float16* Qh = Q + (size_t)bh * SD * HDD;
  const _Float16* Kh = K + (size_t)bh * SD * HDD;
  const _Float16* Vh = VT + (size_t)bh * HDD * SD;

  __shared__ __attribute__((aligned(16))) _Float16 Ks[2][2][64][32];
  __shared__ __attribute__((aligned(16))) _Float16 Vs[2][2][64][32];
  __shared__ __attribute__((aligned(16))) _Float16 P_lds[4][16][64];

  const int grow = lane >> 2;
  const int gswz = (((lane & 3) ^ ((lane >> 3) & 3)) * 8);

  auto stage_k = [&](int b, int kv0) {
#pragma unroll
    for (int kf = 0; kf < 2; kf++) {
      const _Float16* gk = Kh + (size_t)(kv0 + wv * 16 + grow) * HDD + kf * 32 + gswz;
      __builtin_amdgcn_global_load_lds(
          (__attribute__((address_space(1))) void*)gk,
          (__attribute__((address_space(3))) void*)(&Ks[b][kf][wv * 16][0]), 16, 0, 0);
    }
  };
  auto stage_v = [&](int b, int kv0) {
#pragma unroll
    for (int kf = 0; kf < 2; kf++) {
      const _Float16* gv = Vh + (size_t)(wv * 16 + grow) * SD + kv0 + kf * 32 + gswz;
      __builtin_amdgcn_global_load_lds(
          (__attribute__((address_space(1))) void*)gv,
          (__attribute__((address_space(3))) void*)(&Vs[b][kf][wv * 16][0]), 16, 0, 0);
    }
  };

  const int fswz = (lg ^ ((lr >> 1) & 3)) * 8;
  const int pwkey = lg << 1;
  const int prkey = ((lr >> 2) & 3) << 1;

  // Q fragments first (oldest vmem ops -> completed by the first counted wait)
  f16x8 qf[2];
#pragma unroll
  for (int kf = 0; kf < 2; kf++)
    qf[kf] = *(const f16x8*)(Qh + (size_t)(q0 + lr) * HDD + kf * 32 + lg * 8);

  f32x4 acc[4];
  float mrun[4], lsum[4];
#pragma unroll
  for (int i = 0; i < 4; i++) {
    acc[i] = (f32x4){0.f, 0.f, 0.f, 0.f};
    mrun[i] = -1e30f;
    lsum[i] = 0.f;
  }

  // prologue: K(0),V(0)  (per-wave vmem order: Q,Q, K,K, V,V)
  stage_k(0, 0);
  stage_v(0, 0);
  int cur = 0;

  for (int t = 0; t < SD / 64; ++t) {
    const int nkv = ((t + 1) & (SD / 64 - 1)) * 64;  // wrap: dummy loads keep counts uniform

    asm volatile("s_waitcnt vmcnt(2)" ::: "memory");  // K(t) complete (V(t) may fly)
    __builtin_amdgcn_s_barrier();                     // all waves done with prev buffers
    stage_k(cur ^ 1, nkv);                            // issue K(t+1)

    // ---- S = Q K^T (rows=q, cols=key); values already in log2 units ----
    f32x4 sc[4];
#pragma unroll
    for (int nt = 0; nt < 4; nt++) sc[nt] = (f32x4){0.f, 0.f, 0.f, 0.f};
#pragma unroll
    for (int nt = 0; nt < 4; nt++) {
#pragma unroll
      for (int kf = 0; kf < 2; kf++) {
        f16x8 kfr = *(const f16x8*)&Ks[cur][kf][nt * 16 + lr][fswz];
        sc[nt] = mfma_f16(qf[kf], kfr, sc[nt]);
      }
    }
    // ---- online softmax (row = 4*lg + r, col = nt*16 + lr) ----
    float tmax[4];
#pragma unroll
    for (int r = 0; r < 4; r++)
      tmax[r] = fmaxf(fmaxf(fmaxf(sc[0][r], sc[1][r]), sc[2][r]), sc[3][r]);  // v_max3+v_max
#pragma unroll
    for (int off = 1; off < 16; off <<= 1)
#pragma unroll
      for (int r = 0; r < 4; r++) tmax[r] = fmaxf(tmax[r], __shfl_xor(tmax[r], off));

    float need = fmaxf(fmaxf(tmax[0] - mrun[0], tmax[1] - mrun[1]),
                       fmaxf(tmax[2] - mrun[2], tmax[3] - mrun[3]));
    if (__any(need > 8.0f)) {
#pragma unroll
      for (int r = 0; r < 4; r++) {
        float mn = fmaxf(mrun[r], tmax[r]);
        float fm = exp2f(mrun[r] - mn);
        mrun[r] = mn;
        lsum[r] *= fm;
#pragma unroll
        for (int ntd = 0; ntd < 4; ntd++) acc[ntd][r] *= fm;
      }
    }

    float p[4][4];
#pragma unroll
    for (int nt = 0; nt < 4; nt++)
#pragma unroll
      for (int r = 0; r < 4; r++) {
        p[nt][r] = exp2f(sc[nt][r] - mrun[r]);
        lsum[r] += p[nt][r];  // per-lane partial; cross-lane reduce deferred
      }

    asm volatile("s_waitcnt vmcnt(2)" ::: "memory");  // V(t) complete (K(t+1) may fly)
    stage_v(cur ^ 1, nkv);                            // issue V(t+1)

    // ---- stage P (wave-private, swizzled, no barrier) ----
#pragma unroll
    for (int nt = 0; nt < 4; nt++)
#pragma unroll
      for (int r = 0; r < 4; r++) {
        int pslot = ((nt * 2 + (lr >> 3)) ^ pwkey);
        P_lds[wv][lg * 4 + r][pslot * 8 + (lr & 7)] = (_Float16)p[nt][r];
      }
    // ---- O += P V ----
#pragma unroll
    for (int kf = 0; kf < 2; kf++) {
      f16x8 pf = *(const f16x8*)&P_lds[wv][lr][((kf * 4 + lg) ^ prkey) * 8];
#pragma unroll
      for (int ntd = 0; ntd < 4; ntd++) {
        f16x8 vf = *(const f16x8*)&Vs[cur][kf][ntd * 16 + lr][fswz];
        acc[ntd] = mfma_f16(pf, vf, acc[ntd]);
      }
    }
    cur ^= 1;
  }

  // ---- epilogue: deferred cross-lane sum reduce, normalize, write ----
#pragma unroll
  for (int off = 1; off < 16; off <<= 1)
#pragma unroll
    for (int r = 0; r < 4; r++) lsum[r] += __shfl_xor(lsum[r], off);

  const int b = bh >> 4, h = bh & 15;
#pragma unroll
  for (int r = 0; r < 4; r++) {
    float inv = 1.0f / lsum[r];
    int srow = q0 + lg * 4 + r;
#pragma unroll
    for (int ntd = 0; ntd < 4; ntd++) {
      int col = h * 64 + ntd * 16 + lr;
      AO[((size_t)(b * SD + srow)) * HDIM + col] = (_Float16)(acc[ntd][r] * inv);
    }
  }
}

extern "C" void kernel_launch(void* const* d_in, const int* in_sizes, int n_in,
                              void* d_out, int out_size, void* d_ws, size_t ws_size,
                              hipStream_t stream) {
  const float* x  = (const float*)d_in[0];
  const float* Wq = (const float*)d_in[1];
  const float* bq = (const float*)d_in[2];
  const float* Wk = (const float*)d_in[3];
  const float* bk = (const float*)d_in[4];
  const float* Wv = (const float*)d_in[5];
  const float* bv = (const float*)d_in[6];
  const float* Wo = (const float*)d_in[7];
  const float* bo = (const float*)d_in[8];
  float* out = (float*)d_out;

  _Float16* xb  = (_Float16*)d_ws;            // 4M
  _Float16* wqb = xb + 4 * 1024 * 1024;       // 1M
  _Float16* wkb = wqb + 1024 * 1024;
  _Float16* wvb = wkb + 1024 * 1024;
  _Float16* wob = wvb + 1024 * 1024;
  _Float16* Qb  = wob + 1024 * 1024;          // 4M  [bh][s][d]  (pre-scaled)
  _Float16* Kb  = Qb + 4 * 1024 * 1024;       // 4M  [bh][s][d]
  _Float16* Vt  = Kb + 4 * 1024 * 1024;       // 4M  [bh][d][s]
  _Float16* AOb = Vt + 4 * 1024 * 1024;       // 4M  [token][H]

  convert_kernel<<<dim3(1024), dim3(256), 0, stream>>>(x, Wq, Wk, Wv, Wo, xb);
  gemm_qkv<<<dim3(768), dim3(256), 0, stream>>>(xb, wqb, wkb, wvb, bq, bk, bv, Qb, Kb, Vt);
  attn_kernel<<<dim3(32, 32), dim3(256), 0, stream>>>(Qb, Kb, Vt, AOb);
  gemm_out<<<dim3(256), dim3(256), 0, stream>>>(AOb, wob, bo, out);
}

// Round 10
// 155.485 us; speedup vs baseline: 1.9850x; 1.0916x over previous
//
#include <hip/hip_runtime.h>

// MultiHeadAttention: B=2, S=2048, H=1024, NH=16, HD=64
// Pipeline: [convert f32->f16] -> [fused QKV GEMM (V transposed, Q pre-scaled)]
//           -> [flash attention v5: swapped QK^T, key-permuted V storage,
//               in-register P (no P LDS), 1 barrier + vmcnt(0)/tile]
//           -> [output GEMM f32]
// (identical to round-9 source; round 9 was a container infra failure)

#define BD 2
#define SD 2048
#define HDIM 1024
#define NHD 16
#define HDD 64
#define NTOK 4096  // BD*SD
#define QSCALE 0.1803368801111204f  // (1/sqrt(64)) * log2(e), folded into Q

typedef float f32x4 __attribute__((ext_vector_type(4)));
typedef _Float16 f16x8 __attribute__((ext_vector_type(8)));
typedef _Float16 f16x4 __attribute__((ext_vector_type(4)));

__device__ __forceinline__ f32x4 mfma_f16(f16x8 a, f16x8 b, f32x4 c) {
  return __builtin_amdgcn_mfma_f32_16x16x32_f16(a, b, c, 0, 0, 0);
}

// ---------------- convert f32 -> f16 ----------------
__global__ void convert_kernel(const float* __restrict__ x,
                               const float* __restrict__ wq, const float* __restrict__ wk,
                               const float* __restrict__ wv, const float* __restrict__ wo,
                               _Float16* __restrict__ dst) {
  const int total4 = (8 * 1024 * 1024) / 4;
  for (int idx = blockIdx.x * blockDim.x + threadIdx.x; idx < total4;
       idx += gridDim.x * blockDim.x) {
    int e = idx * 4;
    const float* s;
    if (e < 4 * 1024 * 1024) {
      s = x + e;
    } else {
      int w = (e - 4 * 1024 * 1024) >> 20;
      int off = e & 1048575;
      s = (w == 0 ? wq : w == 1 ? wk : w == 2 ? wv : wo) + off;
    }
    float4 v = *(const float4*)s;
    f16x4 h;
    h[0] = (_Float16)v.x; h[1] = (_Float16)v.y;
    h[2] = (_Float16)v.z; h[3] = (_Float16)v.w;
    *(f16x4*)(dst + e) = h;
  }
}

// ---------------- 128x128 GEMM mainloop (C = A * B^T form) ----------------
__device__ __forceinline__ void gemm_mainloop(
    const _Float16* __restrict__ Ap, const _Float16* __restrict__ Bp,
    int i0, int j0, _Float16* As, _Float16* Bs, f32x4 acc[4][4]) {
  const int tid = threadIdx.x;
  const int wid = tid >> 6, lane = tid & 63;
  const int lr = lane & 15, lg = lane >> 4;
  const int wm = wid >> 1, wn = wid & 1;
  const int srow = lane >> 2;
  const int scol = (lane & 3) * 8;

  for (int k0 = 0; k0 < HDIM; k0 += 32) {
#pragma unroll
    for (int it = 0; it < 2; ++it) {
      int rb = (wid * 2 + it) * 16;
      const _Float16* ga = Ap + (size_t)(i0 + rb + srow) * HDIM + k0 + scol;
      const _Float16* gb = Bp + (size_t)(j0 + rb + srow) * HDIM + k0 + scol;
      __builtin_amdgcn_global_load_lds(
          (__attribute__((address_space(1))) void*)ga,
          (__attribute__((address_space(3))) void*)(As + (wid * 2 + it) * 512), 16, 0, 0);
      __builtin_amdgcn_global_load_lds(
          (__attribute__((address_space(1))) void*)gb,
          (__attribute__((address_space(3))) void*)(Bs + (wid * 2 + it) * 512), 16, 0, 0);
    }
    __syncthreads();
    f16x8 af[4], bf[4];
#pragma unroll
    for (int mt = 0; mt < 4; mt++)
      af[mt] = *(const f16x8*)(As + (wm * 64 + mt * 16 + lr) * 32 + lg * 8);
#pragma unroll
    for (int nt = 0; nt < 4; nt++)
      bf[nt] = *(const f16x8*)(Bs + (wn * 64 + nt * 16 + lr) * 32 + lg * 8);
#pragma unroll
    for (int mt = 0; mt < 4; mt++)
#pragma unroll
      for (int nt = 0; nt < 4; nt++)
        acc[mt][nt] = mfma_f16(af[mt], bf[nt], acc[mt][nt]);
    __syncthreads();
  }
}

// ---------------- fused QKV projection ----------------
__global__ __launch_bounds__(256) void gemm_qkv(
    const _Float16* __restrict__ xb,
    const _Float16* __restrict__ wqb, const _Float16* __restrict__ wkb,
    const _Float16* __restrict__ wvb,
    const float* __restrict__ bq, const float* __restrict__ bk,
    const float* __restrict__ bv,
    _Float16* __restrict__ Qo, _Float16* __restrict__ Ko, _Float16* __restrict__ Vt) {
  __shared__ __attribute__((aligned(16))) _Float16 As[128 * 32];
  __shared__ __attribute__((aligned(16))) _Float16 Bs[128 * 32];
  const int bx = blockIdx.x;
  const int mat = bx >> 8;  // 0=Q, 1=K, 2=V
  const int sub = bx & 255;
  const _Float16 *Ap, *Bp;
  int i0, j0;
  if (mat < 2) {
    Ap = xb; Bp = (mat ? wkb : wqb);
    i0 = (sub >> 3) * 128;
    j0 = (sub & 7) * 128;
  } else {
    Ap = wvb; Bp = xb;
    i0 = (sub & 7) * 128;
    j0 = (sub >> 3) * 128;
  }
  f32x4 acc[4][4];
#pragma unroll
  for (int a = 0; a < 4; a++)
#pragma unroll
    for (int b = 0; b < 4; b++) acc[a][b] = (f32x4){0.f, 0.f, 0.f, 0.f};

  gemm_mainloop(Ap, Bp, i0, j0, As, Bs, acc);

  const int tid = threadIdx.x;
  const int wid = tid >> 6, lane = tid & 63;
  const int lr = lane & 15, lg = lane >> 4;
  const int wm = wid >> 1, wn = wid & 1;
  const float* bias = (mat == 0 ? bq : mat == 1 ? bk : bv);

#pragma unroll
  for (int mt = 0; mt < 4; mt++) {
#pragma unroll
    for (int nt = 0; nt < 4; nt++) {
      int i = i0 + wm * 64 + mt * 16 + 4 * lg;
      int j = j0 + wn * 64 + nt * 16 + lr;
      if (mat < 2) {
        float bj = bias[j];
        int h = j >> 6, d = j & 63;
        _Float16* dst = (mat ? Ko : Qo);
        float scl = (mat == 0) ? QSCALE : 1.0f;
#pragma unroll
        for (int r = 0; r < 4; r++) {
          int tok = i + r;
          int b = tok >> 11, s = tok & 2047;
          dst[(((size_t)(b * NHD + h)) * SD + s) * HDD + d] =
              (_Float16)((acc[mt][nt][r] + bj) * scl);
        }
      } else {
        int tok = j;
        int b = tok >> 11, s = tok & 2047;
#pragma unroll
        for (int r = 0; r < 4; r++) {
          int wr = i + r;
          int h = wr >> 6, d = wr & 63;
          Vt[((size_t)(b * NHD + h) * HDD + d) * SD + s] =
              (_Float16)(acc[mt][nt][r] + bias[wr]);
        }
      }
    }
  }
}

// ---------------- output projection: out = attn @ Wo^T + bo (f32) ----------------
__global__ __launch_bounds__(256) void gemm_out(
    const _Float16* __restrict__ attn, const _Float16* __restrict__ wob,
    const float* __restrict__ bo, float* __restrict__ out) {
  __shared__ __attribute__((aligned(16))) _Float16 As[128 * 32];
  __shared__ __attribute__((aligned(16))) _Float16 Bs[128 * 32];
  const int sub = blockIdx.x;
  const int i0 = (sub >> 3) * 128, j0 = (sub & 7) * 128;
  f32x4 acc[4][4];
#pragma unroll
  for (int a = 0; a < 4; a++)
#pragma unroll
    for (int b = 0; b < 4; b++) acc[a][b] = (f32x4){0.f, 0.f, 0.f, 0.f};

  gemm_mainloop(attn, wob, i0, j0, As, Bs, acc);

  const int tid = threadIdx.x;
  const int wid = tid >> 6, lane = tid & 63;
  const int lr = lane & 15, lg = lane >> 4;
  const int wm = wid >> 1, wn = wid & 1;
#pragma unroll
  for (int mt = 0; mt < 4; mt++) {
#pragma unroll
    for (int nt = 0; nt < 4; nt++) {
      int i = i0 + wm * 64 + mt * 16 + 4 * lg;
      int j = j0 + wn * 64 + nt * 16 + lr;
      float bj = bo[j];
#pragma unroll
      for (int r = 0; r < 4; r++)
        out[(size_t)(i + r) * HDIM + j] = acc[mt][nt][r] + bj;
    }
  }
}

// ---------------- flash attention v5 ----------------
// Swapped QK^T: sc = mfma(K, Q) -> lane owns ONE q-row (q = q0+lr), 16 key
// scores (key = 16nt+4lg+r). Row reduce = in-lane tree + 2 shfls; mrun/lsum
// scalar. V stored with key-permutation pi(pos 32kf+8lg+s) = key
// 32kf+16(s>>2)+4lg+(s&3), applied via 4B global_load_lds source addresses,
// so each lane's own p-values (cast to f16) ARE the PV B-fragment. No P LDS.
// O^T accumulated: acc[ntd][r] = O[q=lr][d=ntd*16+4lg+r].
// Schedule: stage(t+1) issued right after barrier(t); wait vmcnt(0) at top of
// t+1 (a full tile after issue -> nearly free) + 1 barrier = race-free dbuf.
__global__ __launch_bounds__(256) void attn_kernel(
    const _Float16* __restrict__ Q, const _Float16* __restrict__ K,
    const _Float16* __restrict__ VT, _Float16* __restrict__ AO) {
  const int bh = blockIdx.y, qb = blockIdx.x;
  const int tid = threadIdx.x, wv = tid >> 6, lane = tid & 63;
  const int lr = lane & 15, lg = lane >> 4;
  const int q0 = qb * 64 + wv * 16;
  const _Float16* Qh = Q + (size_t)bh * SD * HDD;
  const _Float16* Kh = K + (size_t)bh * SD * HDD;
  const _Float16* Vh = VT + (size_t)bh * HDD * SD;

  __shared__ __attribute__((aligned(16))) _Float16 Ks[2][2][64][32];  // [buf][kf][key][d-half]
  __shared__ __attribute__((aligned(16))) _Float16 Vs[2][2][64][32];  // [buf][kf][d][pos]

  // K staging (16B granules, 16 rows/instr): bank swizzle via source column
  const int krow = lane >> 2;
  const int kswz = (((lane & 3) ^ ((lane >> 3) & 3)) * 8);

  // V staging (4B granules = 2 keys, 4 rows/instr): key-permutation pi +
  // bank swizzle, all applied to the global source address.
  const int m  = lane & 15;   // pos-pair index within row
  const int u  = m & 3;       // sub-pair within 16B slot
  const int sg = m >> 2;      // physical 16B slot
  const int r4 = lane >> 4;   // row within 4-row group
  const int c2 = (r4 >> 1) & 1;
  // logical slot lam = sg ^ k(row); k(row) = (2i + c2)&3 -> even i: c2, odd i: c2^2
  const int keyoff_e = 16 * (u >> 1) + 4 * (sg ^ c2)       + 2 * (u & 1);
  const int keyoff_o = 16 * (u >> 1) + 4 * (sg ^ (c2 | 2)) + 2 * (u & 1);
  const _Float16* Vrow[4];
#pragma unroll
  for (int i = 0; i < 4; i++)
    Vrow[i] = Vh + (size_t)(wv * 16 + i * 4 + r4) * SD + ((i & 1) ? keyoff_o : keyoff_e);

  auto stage = [&](int b, int kv0) {
#pragma unroll
    for (int kf = 0; kf < 2; kf++) {
      const _Float16* gk = Kh + (size_t)(kv0 + wv * 16 + krow) * HDD + kf * 32 + kswz;
      __builtin_amdgcn_global_load_lds(
          (__attribute__((address_space(1))) void*)gk,
          (__attribute__((address_space(3))) void*)(&Ks[b][kf][wv * 16][0]), 16, 0, 0);
    }
#pragma unroll
    for (int kf = 0; kf < 2; kf++)
#pragma unroll
      for (int i = 0; i < 4; i++) {
        const _Float16* gv = Vrow[i] + kv0 + kf * 32;
        __builtin_amdgcn_global_load_lds(
            (__attribute__((address_space(1))) void*)gv,
            (__attribute__((address_space(3))) void*)(&Vs[b][kf][wv * 16 + i * 4][0]), 4, 0, 0);
      }
  };

  // fragment-read physical slot (row R, R&15=lr): lg ^ ((lr>>1)&3)
  const int fswz = (lg ^ ((lr >> 1) & 3)) * 8;

  // Q fragments (pre-scaled by QSCALE): B-operand, lane lr = q-row q0+lr
  f16x8 qf[2];
#pragma unroll
  for (int kf = 0; kf < 2; kf++)
    qf[kf] = *(const f16x8*)(Qh + (size_t)(q0 + lr) * HDD + kf * 32 + lg * 8);

  f32x4 acc[4];
#pragma unroll
  for (int i = 0; i < 4; i++) acc[i] = (f32x4){0.f, 0.f, 0.f, 0.f};
  float mrun = -1e30f, lsum = 0.f;

  stage(0, 0);
  int cur = 0;

  for (int t = 0; t < SD / 64; ++t) {
    asm volatile("s_waitcnt vmcnt(0)" ::: "memory");  // tile t staged (issued a full tile ago)
    __builtin_amdgcn_s_barrier();                     // all waves: staging done, prev reads done
    stage(cur ^ 1, ((t + 1) & (SD / 64 - 1)) * 64);   // issue t+1 (wrap: dummy, keeps pattern)

    // ---- S^T = K Q^T: lane = (q=lr), keys 16nt+4lg+r (log2 units) ----
    f32x4 sc[4];
#pragma unroll
    for (int nt = 0; nt < 4; nt++) sc[nt] = (f32x4){0.f, 0.f, 0.f, 0.f};
#pragma unroll
    for (int nt = 0; nt < 4; nt++)
#pragma unroll
      for (int kf = 0; kf < 2; kf++) {
        f16x8 kfr = *(const f16x8*)&Ks[cur][kf][nt * 16 + lr][fswz];
        sc[nt] = mfma_f16(kfr, qf[kf], sc[nt]);  // swapped operands
      }

    // ---- online softmax, all per-lane scalar ----
    float tm = sc[0][0];
#pragma unroll
    for (int nt = 0; nt < 4; nt++)
#pragma unroll
      for (int r = 0; r < 4; r++) tm = fmaxf(tm, sc[nt][r]);
    tm = fmaxf(tm, __shfl_xor(tm, 16));
    tm = fmaxf(tm, __shfl_xor(tm, 32));

    if (__any(tm - mrun > 8.0f)) {  // defer-max (THR=8)
      float mn = fmaxf(mrun, tm);
      float fm = exp2f(mrun - mn);
      mrun = mn;
      lsum *= fm;
#pragma unroll
      for (int ntd = 0; ntd < 4; ntd++)
#pragma unroll
        for (int r = 0; r < 4; r++) acc[ntd][r] *= fm;
    }

    float p[4][4];
#pragma unroll
    for (int nt = 0; nt < 4; nt++)
#pragma unroll
      for (int r = 0; r < 4; r++) {
        p[nt][r] = exp2f(sc[nt][r] - mrun);
        lsum += p[nt][r];
      }

    // ---- O^T += V^T P: lane's own p IS its B-fragment (via V key-perm) ----
#pragma unroll
    for (int kf = 0; kf < 2; kf++) {
      f16x8 pb;
#pragma unroll
      for (int r = 0; r < 4; r++) {
        pb[r]     = (_Float16)p[2 * kf][r];
        pb[4 + r] = (_Float16)p[2 * kf + 1][r];
      }
#pragma unroll
      for (int ntd = 0; ntd < 4; ntd++) {
        f16x8 vf = *(const f16x8*)&Vs[cur][kf][ntd * 16 + lr][fswz];
        acc[ntd] = mfma_f16(vf, pb, acc[ntd]);
      }
    }
    cur ^= 1;
  }

  // ---- epilogue: lsum reduce (2 shfl), normalize, write O ----
  lsum += __shfl_xor(lsum, 16);
  lsum += __shfl_xor(lsum, 32);
  float inv = 1.0f / lsum;

  const int b = bh >> 4, h = bh & 15;
  _Float16* aoRow = AO + (size_t)(b * SD + q0 + lr) * HDIM + h * 64;
#pragma unroll
  for (int ntd = 0; ntd < 4; ntd++) {
    f16x4 o;
#pragma unroll
    for (int r = 0; r < 4; r++) o[r] = (_Float16)(acc[ntd][r] * inv);
    *(f16x4*)(aoRow + ntd * 16 + 4 * lg) = o;
  }
}

extern "C" void kernel_launch(void* const* d_in, const int* in_sizes, int n_in,
                              void* d_out, int out_size, void* d_ws, size_t ws_size,
                              hipStream_t stream) {
  const float* x  = (const float*)d_in[0];
  const float* Wq = (const float*)d_in[1];
  const float* bq = (const float*)d_in[2];
  const float* Wk = (const float*)d_in[3];
  const float* bk = (const float*)d_in[4];
  const float* Wv = (const float*)d_in[5];
  const float* bv = (const float*)d_in[6];
  const float* Wo = (const float*)d_in[7];
  const float* bo = (const float*)d_in[8];
  float* out = (float*)d_out;

  _Float16* xb  = (_Float16*)d_ws;            // 4M
  _Float16* wqb = xb + 4 * 1024 * 1024;       // 1M
  _Float16* wkb = wqb + 1024 * 1024;
  _Float16* wvb = wkb + 1024 * 1024;
  _Float16* wob = wvb + 1024 * 1024;
  _Float16* Qb  = wob + 1024 * 1024;          // 4M  [bh][s][d]  (pre-scaled)
  _Float16* Kb  = Qb + 4 * 1024 * 1024;       // 4M  [bh][s][d]
  _Float16* Vt  = Kb + 4 * 1024 * 1024;       // 4M  [bh][d][s]
  _Float16* AOb = Vt + 4 * 1024 * 1024;       // 4M  [token][H]

  convert_kernel<<<dim3(1024), dim3(256), 0, stream>>>(x, Wq, Wk, Wv, Wo, xb);
  gemm_qkv<<<dim3(768), dim3(256), 0, stream>>>(xb, wqb, wkb, wvb, bq, bk, bv, Qb, Kb, Vt);
  attn_kernel<<<dim3(32, 32), dim3(256), 0, stream>>>(Qb, Kb, Vt, AOb);
  gemm_out<<<dim3(256), dim3(256), 0, stream>>>(AOb, wob, bo, out);
}

// Round 13
// 140.471 us; speedup vs baseline: 2.1972x; 1.1069x over previous
//
#include <hip/hip_runtime.h>

// MultiHeadAttention: B=2, S=2048, H=1024, NH=16, HD=64
// Pipeline: [convert f32->f16] -> [fused QKV GEMM (V transposed, Q pre-scaled)]
//           -> [flash attention v6: swapped QK^T, key-permuted V, in-register P,
//               8-wave blocks (128 q-rows), packed cvt] -> [output GEMM f32]
// (round-12 fix: cvt_pkrtz returns __fp16x2 -> bit_cast into the f16 fragment)

#define BD 2
#define SD 2048
#define HDIM 1024
#define NHD 16
#define HDD 64
#define NTOK 4096  // BD*SD
#define QSCALE 0.1803368801111204f  // (1/sqrt(64)) * log2(e), folded into Q

typedef float f32x4 __attribute__((ext_vector_type(4)));
typedef _Float16 f16x8 __attribute__((ext_vector_type(8)));
typedef _Float16 f16x4 __attribute__((ext_vector_type(4)));
typedef __fp16 fp16x2 __attribute__((ext_vector_type(2)));

__device__ __forceinline__ f32x4 mfma_f16(f16x8 a, f16x8 b, f32x4 c) {
  return __builtin_amdgcn_mfma_f32_16x16x32_f16(a, b, c, 0, 0, 0);
}

// pack two f32 -> one u32 of 2 f16 (RTZ), as a raw 32-bit word
__device__ __forceinline__ unsigned int pk2h(float lo, float hi) {
  fp16x2 v = __builtin_amdgcn_cvt_pkrtz(lo, hi);
  return __builtin_bit_cast(unsigned int, v);
}

// ---------------- convert f32 -> f16 ----------------
__global__ void convert_kernel(const float* __restrict__ x,
                               const float* __restrict__ wq, const float* __restrict__ wk,
                               const float* __restrict__ wv, const float* __restrict__ wo,
                               _Float16* __restrict__ dst) {
  const int total4 = (8 * 1024 * 1024) / 4;
  for (int idx = blockIdx.x * blockDim.x + threadIdx.x; idx < total4;
       idx += gridDim.x * blockDim.x) {
    int e = idx * 4;
    const float* s;
    if (e < 4 * 1024 * 1024) {
      s = x + e;
    } else {
      int w = (e - 4 * 1024 * 1024) >> 20;
      int off = e & 1048575;
      s = (w == 0 ? wq : w == 1 ? wk : w == 2 ? wv : wo) + off;
    }
    float4 v = *(const float4*)s;
    f16x4 h;
    h[0] = (_Float16)v.x; h[1] = (_Float16)v.y;
    h[2] = (_Float16)v.z; h[3] = (_Float16)v.w;
    *(f16x4*)(dst + e) = h;
  }
}

// ---------------- 128x128 GEMM mainloop (C = A * B^T form) ----------------
__device__ __forceinline__ void gemm_mainloop(
    const _Float16* __restrict__ Ap, const _Float16* __restrict__ Bp,
    int i0, int j0, _Float16* As, _Float16* Bs, f32x4 acc[4][4]) {
  const int tid = threadIdx.x;
  const int wid = tid >> 6, lane = tid & 63;
  const int lr = lane & 15, lg = lane >> 4;
  const int wm = wid >> 1, wn = wid & 1;
  const int srow = lane >> 2;
  const int scol = (lane & 3) * 8;

  for (int k0 = 0; k0 < HDIM; k0 += 32) {
#pragma unroll
    for (int it = 0; it < 2; ++it) {
      int rb = (wid * 2 + it) * 16;
      const _Float16* ga = Ap + (size_t)(i0 + rb + srow) * HDIM + k0 + scol;
      const _Float16* gb = Bp + (size_t)(j0 + rb + srow) * HDIM + k0 + scol;
      __builtin_amdgcn_global_load_lds(
          (__attribute__((address_space(1))) void*)ga,
          (__attribute__((address_space(3))) void*)(As + (wid * 2 + it) * 512), 16, 0, 0);
      __builtin_amdgcn_global_load_lds(
          (__attribute__((address_space(1))) void*)gb,
          (__attribute__((address_space(3))) void*)(Bs + (wid * 2 + it) * 512), 16, 0, 0);
    }
    __syncthreads();
    f16x8 af[4], bf[4];
#pragma unroll
    for (int mt = 0; mt < 4; mt++)
      af[mt] = *(const f16x8*)(As + (wm * 64 + mt * 16 + lr) * 32 + lg * 8);
#pragma unroll
    for (int nt = 0; nt < 4; nt++)
      bf[nt] = *(const f16x8*)(Bs + (wn * 64 + nt * 16 + lr) * 32 + lg * 8);
#pragma unroll
    for (int mt = 0; mt < 4; mt++)
#pragma unroll
      for (int nt = 0; nt < 4; nt++)
        acc[mt][nt] = mfma_f16(af[mt], bf[nt], acc[mt][nt]);
    __syncthreads();
  }
}

// ---------------- fused QKV projection ----------------
__global__ __launch_bounds__(256) void gemm_qkv(
    const _Float16* __restrict__ xb,
    const _Float16* __restrict__ wqb, const _Float16* __restrict__ wkb,
    const _Float16* __restrict__ wvb,
    const float* __restrict__ bq, const float* __restrict__ bk,
    const float* __restrict__ bv,
    _Float16* __restrict__ Qo, _Float16* __restrict__ Ko, _Float16* __restrict__ Vt) {
  __shared__ __attribute__((aligned(16))) _Float16 As[128 * 32];
  __shared__ __attribute__((aligned(16))) _Float16 Bs[128 * 32];
  const int bx = blockIdx.x;
  const int mat = bx >> 8;  // 0=Q, 1=K, 2=V
  const int sub = bx & 255;
  const _Float16 *Ap, *Bp;
  int i0, j0;
  if (mat < 2) {
    Ap = xb; Bp = (mat ? wkb : wqb);
    i0 = (sub >> 3) * 128;
    j0 = (sub & 7) * 128;
  } else {
    Ap = wvb; Bp = xb;
    i0 = (sub & 7) * 128;
    j0 = (sub >> 3) * 128;
  }
  f32x4 acc[4][4];
#pragma unroll
  for (int a = 0; a < 4; a++)
#pragma unroll
    for (int b = 0; b < 4; b++) acc[a][b] = (f32x4){0.f, 0.f, 0.f, 0.f};

  gemm_mainloop(Ap, Bp, i0, j0, As, Bs, acc);

  const int tid = threadIdx.x;
  const int wid = tid >> 6, lane = tid & 63;
  const int lr = lane & 15, lg = lane >> 4;
  const int wm = wid >> 1, wn = wid & 1;
  const float* bias = (mat == 0 ? bq : mat == 1 ? bk : bv);

#pragma unroll
  for (int mt = 0; mt < 4; mt++) {
#pragma unroll
    for (int nt = 0; nt < 4; nt++) {
      int i = i0 + wm * 64 + mt * 16 + 4 * lg;
      int j = j0 + wn * 64 + nt * 16 + lr;
      if (mat < 2) {
        float bj = bias[j];
        int h = j >> 6, d = j & 63;
        _Float16* dst = (mat ? Ko : Qo);
        float scl = (mat == 0) ? QSCALE : 1.0f;
#pragma unroll
        for (int r = 0; r < 4; r++) {
          int tok = i + r;
          int b = tok >> 11, s = tok & 2047;
          dst[(((size_t)(b * NHD + h)) * SD + s) * HDD + d] =
              (_Float16)((acc[mt][nt][r] + bj) * scl);
        }
      } else {
        int tok = j;
        int b = tok >> 11, s = tok & 2047;
#pragma unroll
        for (int r = 0; r < 4; r++) {
          int wr = i + r;
          int h = wr >> 6, d = wr & 63;
          Vt[((size_t)(b * NHD + h) * HDD + d) * SD + s] =
              (_Float16)(acc[mt][nt][r] + bias[wr]);
        }
      }
    }
  }
}

// ---------------- output projection: out = attn @ Wo^T + bo (f32) ----------------
__global__ __launch_bounds__(256) void gemm_out(
    const _Float16* __restrict__ attn, const _Float16* __restrict__ wob,
    const float* __restrict__ bo, float* __restrict__ out) {
  __shared__ __attribute__((aligned(16))) _Float16 As[128 * 32];
  __shared__ __attribute__((aligned(16))) _Float16 Bs[128 * 32];
  const int sub = blockIdx.x;
  const int i0 = (sub >> 3) * 128, j0 = (sub & 7) * 128;
  f32x4 acc[4][4];
#pragma unroll
  for (int a = 0; a < 4; a++)
#pragma unroll
    for (int b = 0; b < 4; b++) acc[a][b] = (f32x4){0.f, 0.f, 0.f, 0.f};

  gemm_mainloop(attn, wob, i0, j0, As, Bs, acc);

  const int tid = threadIdx.x;
  const int wid = tid >> 6, lane = tid & 63;
  const int lr = lane & 15, lg = lane >> 4;
  const int wm = wid >> 1, wn = wid & 1;
#pragma unroll
  for (int mt = 0; mt < 4; mt++) {
#pragma unroll
    for (int nt = 0; nt < 4; nt++) {
      int i = i0 + wm * 64 + mt * 16 + 4 * lg;
      int j = j0 + wn * 64 + nt * 16 + lr;
      float bj = bo[j];
#pragma unroll
      for (int r = 0; r < 4; r++)
        out[(size_t)(i + r) * HDIM + j] = acc[mt][nt][r] + bj;
    }
  }
}

// ---------------- flash attention v6 ----------------
// v5 structure (swapped QK^T, key-permuted V via 4B gload_lds sources, no P LDS)
// with 8-wave blocks: 128 q-rows/block, grid (16,32) = 512 blocks = 2/CU ->
// 16 waves/CU (50% cap); K/V staging split across 8 waves (K:1, V:4 instrs/wave).
// Packed v_cvt_pkrtz for the P->f16 B-fragment (8 instrs vs 16).
__global__ __launch_bounds__(512) void attn_kernel(
    const _Float16* __restrict__ Q, const _Float16* __restrict__ K,
    const _Float16* __restrict__ VT, _Float16* __restrict__ AO) {
  const int bh = blockIdx.y, qb = blockIdx.x;
  const int tid = threadIdx.x, wv = tid >> 6, lane = tid & 63;
  const int lr = lane & 15, lg = lane >> 4;
  const int q0 = qb * 128 + wv * 16;
  const _Float16* Qh = Q + (size_t)bh * SD * HDD;
  const _Float16* Kh = K + (size_t)bh * SD * HDD;
  const _Float16* Vh = VT + (size_t)bh * HDD * SD;

  __shared__ __attribute__((aligned(16))) _Float16 Ks[2][2][64][32];  // [buf][kf][key][d-half]
  __shared__ __attribute__((aligned(16))) _Float16 Vs[2][2][64][32];  // [buf][kf][d][pos]

  // K staging: wave wv stages kf=wv&1, key-rows (wv>>1)*16..+15 (one 16B instr)
  const int krow = lane >> 2;
  const int kswz = (((lane & 3) ^ ((lane >> 3) & 3)) * 8);
  const int kkf = wv & 1, krb = (wv >> 1) * 16;

  // V staging: wave wv stages d-rows wv*8..wv*8+7 per kf (two 4B instrs each).
  // Key-permutation pi + bank swizzle applied to the global source address.
  const int m  = lane & 15;   // pos-pair index within row
  const int u  = m & 3;       // sub-pair within 16B slot
  const int sg = m >> 2;      // physical 16B slot
  const int r4 = lane >> 4;   // row within 4-row group
  const int c2 = (r4 >> 1) & 1;
  const int keyoff_e = 16 * (u >> 1) + 4 * (sg ^ c2)       + 2 * (u & 1);
  const int keyoff_o = 16 * (u >> 1) + 4 * (sg ^ (c2 | 2)) + 2 * (u & 1);
  const _Float16* Vrow[2];
  Vrow[0] = Vh + (size_t)(wv * 8 + 0 + r4) * SD + keyoff_e;
  Vrow[1] = Vh + (size_t)(wv * 8 + 4 + r4) * SD + keyoff_o;

  auto stage = [&](int b, int kv0) {
    const _Float16* gk = Kh + (size_t)(kv0 + krb + krow) * HDD + kkf * 32 + kswz;
    __builtin_amdgcn_global_load_lds(
        (__attribute__((address_space(1))) void*)gk,
        (__attribute__((address_space(3))) void*)(&Ks[b][kkf][krb][0]), 16, 0, 0);
#pragma unroll
    for (int kf = 0; kf < 2; kf++)
#pragma unroll
      for (int i = 0; i < 2; i++) {
        const _Float16* gv = Vrow[i] + kv0 + kf * 32;
        __builtin_amdgcn_global_load_lds(
            (__attribute__((address_space(1))) void*)gv,
            (__attribute__((address_space(3))) void*)(&Vs[b][kf][wv * 8 + i * 4][0]), 4, 0, 0);
      }
  };

  // fragment-read physical slot (row R, R&15=lr): lg ^ ((lr>>1)&3)
  const int fswz = (lg ^ ((lr >> 1) & 3)) * 8;

  // Q fragments (pre-scaled by QSCALE): B-operand, lane lr = q-row q0+lr
  f16x8 qf[2];
#pragma unroll
  for (int kf = 0; kf < 2; kf++)
    qf[kf] = *(const f16x8*)(Qh + (size_t)(q0 + lr) * HDD + kf * 32 + lg * 8);

  f32x4 acc[4];
#pragma unroll
  for (int i = 0; i < 4; i++) acc[i] = (f32x4){0.f, 0.f, 0.f, 0.f};
  float mrun = -1e30f, lsum = 0.f;

  stage(0, 0);
  int cur = 0;

  for (int t = 0; t < SD / 64; ++t) {
    asm volatile("s_waitcnt vmcnt(0)" ::: "memory");  // tile t staged (issued a full tile ago)
    __builtin_amdgcn_s_barrier();                     // all waves: staging done, prev reads done
    stage(cur ^ 1, ((t + 1) & (SD / 64 - 1)) * 64);   // issue t+1 (wrap: dummy, keeps pattern)

    // ---- S^T = K Q^T: lane = (q=lr), keys 16nt+4lg+r (log2 units) ----
    f32x4 sc[4];
#pragma unroll
    for (int nt = 0; nt < 4; nt++) sc[nt] = (f32x4){0.f, 0.f, 0.f, 0.f};
#pragma unroll
    for (int nt = 0; nt < 4; nt++)
#pragma unroll
      for (int kf = 0; kf < 2; kf++) {
        f16x8 kfr = *(const f16x8*)&Ks[cur][kf][nt * 16 + lr][fswz];
        sc[nt] = mfma_f16(kfr, qf[kf], sc[nt]);  // swapped operands
      }

    // ---- online softmax, all per-lane scalar ----
    float tm = sc[0][0];
#pragma unroll
    for (int nt = 0; nt < 4; nt++)
#pragma unroll
      for (int r = 0; r < 4; r++) tm = fmaxf(tm, sc[nt][r]);
    tm = fmaxf(tm, __shfl_xor(tm, 16));
    tm = fmaxf(tm, __shfl_xor(tm, 32));

    if (__any(tm - mrun > 8.0f)) {  // defer-max (THR=8)
      float mn = fmaxf(mrun, tm);
      float fm = exp2f(mrun - mn);
      mrun = mn;
      lsum *= fm;
#pragma unroll
      for (int ntd = 0; ntd < 4; ntd++)
#pragma unroll
        for (int r = 0; r < 4; r++) acc[ntd][r] *= fm;
    }

    float p[4][4];
#pragma unroll
    for (int nt = 0; nt < 4; nt++)
#pragma unroll
      for (int r = 0; r < 4; r++) {
        p[nt][r] = exp2f(sc[nt][r] - mrun);
        lsum += p[nt][r];
      }

    // ---- O^T += V^T P: lane's own p IS its B-fragment (via V key-perm) ----
#pragma unroll
    for (int kf = 0; kf < 2; kf++) {
      unsigned int pw[4];
      pw[0] = pk2h(p[2 * kf][0], p[2 * kf][1]);
      pw[1] = pk2h(p[2 * kf][2], p[2 * kf][3]);
      pw[2] = pk2h(p[2 * kf + 1][0], p[2 * kf + 1][1]);
      pw[3] = pk2h(p[2 * kf + 1][2], p[2 * kf + 1][3]);
      f16x8 pb = __builtin_bit_cast(f16x8, *(unsigned int(*)[4])pw);
#pragma unroll
      for (int ntd = 0; ntd < 4; ntd++) {
        f16x8 vf = *(const f16x8*)&Vs[cur][kf][ntd * 16 + lr][fswz];
        acc[ntd] = mfma_f16(vf, pb, acc[ntd]);
      }
    }
    cur ^= 1;
  }

  // ---- epilogue: lsum reduce (2 shfl), normalize, write O ----
  lsum += __shfl_xor(lsum, 16);
  lsum += __shfl_xor(lsum, 32);
  float inv = 1.0f / lsum;

  const int b = bh >> 4, h = bh & 15;
  _Float16* aoRow = AO + (size_t)(b * SD + q0 + lr) * HDIM + h * 64;
#pragma unroll
  for (int ntd = 0; ntd < 4; ntd++) {
    f16x4 o;
#pragma unroll
    for (int r = 0; r < 4; r++) o[r] = (_Float16)(acc[ntd][r] * inv);
    *(f16x4*)(aoRow + ntd * 16 + 4 * lg) = o;
  }
}

extern "C" void kernel_launch(void* const* d_in, const int* in_sizes, int n_in,
                              void* d_out, int out_size, void* d_ws, size_t ws_size,
                              hipStream_t stream) {
  const float* x  = (const float*)d_in[0];
  const float* Wq = (const float*)d_in[1];
  const float* bq = (const float*)d_in[2];
  const float* Wk = (const float*)d_in[3];
  const float* bk = (const float*)d_in[4];
  const float* Wv = (const float*)d_in[5];
  const float* bv = (const float*)d_in[6];
  const float* Wo = (const float*)d_in[7];
  const float* bo = (const float*)d_in[8];
  float* out = (float*)d_out;

  _Float16* xb  = (_Float16*)d_ws;            // 4M
  _Float16* wqb = xb + 4 * 1024 * 1024;       // 1M
  _Float16* wkb = wqb + 1024 * 1024;
  _Float16* wvb = wkb + 1024 * 1024;
  _Float16* wob = wvb + 1024 * 1024;
  _Float16* Qb  = wob + 1024 * 1024;          // 4M  [bh][s][d]  (pre-scaled)
  _Float16* Kb  = Qb + 4 * 1024 * 1024;       // 4M  [bh][s][d]
  _Float16* Vt  = Kb + 4 * 1024 * 1024;       // 4M  [bh][d][s]
  _Float16* AOb = Vt + 4 * 1024 * 1024;       // 4M  [token][H]

  convert_kernel<<<dim3(1024), dim3(256), 0, stream>>>(x, Wq, Wk, Wv, Wo, xb);
  gemm_qkv<<<dim3(768), dim3(256), 0, stream>>>(xb, wqb, wkb, wvb, bq, bk, bv, Qb, Kb, Vt);
  attn_kernel<<<dim3(16, 32), dim3(512), 0, stream>>>(Qb, Kb, Vt, AOb);
  gemm_out<<<dim3(256), dim3(256), 0, stream>>>(AOb, wob, bo, out);
}

// Round 14
// 139.378 us; speedup vs baseline: 2.2144x; 1.0078x over previous
//
#include <hip/hip_runtime.h>

// MultiHeadAttention: B=2, S=2048, H=1024, NH=16, HD=64
// v7: attn micro-opts — max3/tree reductions, 4 partial lsums, exp2/PV
// interleave per kf-half, s_setprio around MFMA clusters, XCD-aware block map.

#define BD 2
#define SD 2048
#define HDIM 1024
#define NHD 16
#define HDD 64
#define NTOK 4096  // BD*SD
#define QSCALE 0.1803368801111204f  // (1/sqrt(64)) * log2(e), folded into Q

typedef float f32x4 __attribute__((ext_vector_type(4)));
typedef _Float16 f16x8 __attribute__((ext_vector_type(8)));
typedef _Float16 f16x4 __attribute__((ext_vector_type(4)));
typedef __fp16 fp16x2 __attribute__((ext_vector_type(2)));

__device__ __forceinline__ f32x4 mfma_f16(f16x8 a, f16x8 b, f32x4 c) {
  return __builtin_amdgcn_mfma_f32_16x16x32_f16(a, b, c, 0, 0, 0);
}

// pack two f32 -> one u32 of 2 f16 (RTZ)
__device__ __forceinline__ unsigned int pk2h(float lo, float hi) {
  fp16x2 v = __builtin_amdgcn_cvt_pkrtz(lo, hi);
  return __builtin_bit_cast(unsigned int, v);
}

// ---------------- convert f32 -> f16 ----------------
__global__ void convert_kernel(const float* __restrict__ x,
                               const float* __restrict__ wq, const float* __restrict__ wk,
                               const float* __restrict__ wv, const float* __restrict__ wo,
                               _Float16* __restrict__ dst) {
  const int total4 = (8 * 1024 * 1024) / 4;
  for (int idx = blockIdx.x * blockDim.x + threadIdx.x; idx < total4;
       idx += gridDim.x * blockDim.x) {
    int e = idx * 4;
    const float* s;
    if (e < 4 * 1024 * 1024) {
      s = x + e;
    } else {
      int w = (e - 4 * 1024 * 1024) >> 20;
      int off = e & 1048575;
      s = (w == 0 ? wq : w == 1 ? wk : w == 2 ? wv : wo) + off;
    }
    float4 v = *(const float4*)s;
    f16x4 h;
    h[0] = (_Float16)v.x; h[1] = (_Float16)v.y;
    h[2] = (_Float16)v.z; h[3] = (_Float16)v.w;
    *(f16x4*)(dst + e) = h;
  }
}

// ---------------- 128x128 GEMM mainloop (C = A * B^T form) ----------------
__device__ __forceinline__ void gemm_mainloop(
    const _Float16* __restrict__ Ap, const _Float16* __restrict__ Bp,
    int i0, int j0, _Float16* As, _Float16* Bs, f32x4 acc[4][4]) {
  const int tid = threadIdx.x;
  const int wid = tid >> 6, lane = tid & 63;
  const int lr = lane & 15, lg = lane >> 4;
  const int wm = wid >> 1, wn = wid & 1;
  const int srow = lane >> 2;
  const int scol = (lane & 3) * 8;

  for (int k0 = 0; k0 < HDIM; k0 += 32) {
#pragma unroll
    for (int it = 0; it < 2; ++it) {
      int rb = (wid * 2 + it) * 16;
      const _Float16* ga = Ap + (size_t)(i0 + rb + srow) * HDIM + k0 + scol;
      const _Float16* gb = Bp + (size_t)(j0 + rb + srow) * HDIM + k0 + scol;
      __builtin_amdgcn_global_load_lds(
          (__attribute__((address_space(1))) void*)ga,
          (__attribute__((address_space(3))) void*)(As + (wid * 2 + it) * 512), 16, 0, 0);
      __builtin_amdgcn_global_load_lds(
          (__attribute__((address_space(1))) void*)gb,
          (__attribute__((address_space(3))) void*)(Bs + (wid * 2 + it) * 512), 16, 0, 0);
    }
    __syncthreads();
    f16x8 af[4], bf[4];
#pragma unroll
    for (int mt = 0; mt < 4; mt++)
      af[mt] = *(const f16x8*)(As + (wm * 64 + mt * 16 + lr) * 32 + lg * 8);
#pragma unroll
    for (int nt = 0; nt < 4; nt++)
      bf[nt] = *(const f16x8*)(Bs + (wn * 64 + nt * 16 + lr) * 32 + lg * 8);
#pragma unroll
    for (int mt = 0; mt < 4; mt++)
#pragma unroll
      for (int nt = 0; nt < 4; nt++)
        acc[mt][nt] = mfma_f16(af[mt], bf[nt], acc[mt][nt]);
    __syncthreads();
  }
}

// ---------------- fused QKV projection ----------------
__global__ __launch_bounds__(256) void gemm_qkv(
    const _Float16* __restrict__ xb,
    const _Float16* __restrict__ wqb, const _Float16* __restrict__ wkb,
    const _Float16* __restrict__ wvb,
    const float* __restrict__ bq, const float* __restrict__ bk,
    const float* __restrict__ bv,
    _Float16* __restrict__ Qo, _Float16* __restrict__ Ko, _Float16* __restrict__ Vt) {
  __shared__ __attribute__((aligned(16))) _Float16 As[128 * 32];
  __shared__ __attribute__((aligned(16))) _Float16 Bs[128 * 32];
  const int bx = blockIdx.x;
  const int mat = bx >> 8;  // 0=Q, 1=K, 2=V
  const int sub = bx & 255;
  const _Float16 *Ap, *Bp;
  int i0, j0;
  if (mat < 2) {
    Ap = xb; Bp = (mat ? wkb : wqb);
    i0 = (sub >> 3) * 128;
    j0 = (sub & 7) * 128;
  } else {
    Ap = wvb; Bp = xb;
    i0 = (sub & 7) * 128;
    j0 = (sub >> 3) * 128;
  }
  f32x4 acc[4][4];
#pragma unroll
  for (int a = 0; a < 4; a++)
#pragma unroll
    for (int b = 0; b < 4; b++) acc[a][b] = (f32x4){0.f, 0.f, 0.f, 0.f};

  gemm_mainloop(Ap, Bp, i0, j0, As, Bs, acc);

  const int tid = threadIdx.x;
  const int wid = tid >> 6, lane = tid & 63;
  const int lr = lane & 15, lg = lane >> 4;
  const int wm = wid >> 1, wn = wid & 1;
  const float* bias = (mat == 0 ? bq : mat == 1 ? bk : bv);

#pragma unroll
  for (int mt = 0; mt < 4; mt++) {
#pragma unroll
    for (int nt = 0; nt < 4; nt++) {
      int i = i0 + wm * 64 + mt * 16 + 4 * lg;
      int j = j0 + wn * 64 + nt * 16 + lr;
      if (mat < 2) {
        float bj = bias[j];
        int h = j >> 6, d = j & 63;
        _Float16* dst = (mat ? Ko : Qo);
        float scl = (mat == 0) ? QSCALE : 1.0f;
#pragma unroll
        for (int r = 0; r < 4; r++) {
          int tok = i + r;
          int b = tok >> 11, s = tok & 2047;
          dst[(((size_t)(b * NHD + h)) * SD + s) * HDD + d] =
              (_Float16)((acc[mt][nt][r] + bj) * scl);
        }
      } else {
        int tok = j;
        int b = tok >> 11, s = tok & 2047;
#pragma unroll
        for (int r = 0; r < 4; r++) {
          int wr = i + r;
          int h = wr >> 6, d = wr & 63;
          Vt[((size_t)(b * NHD + h) * HDD + d) * SD + s] =
              (_Float16)(acc[mt][nt][r] + bias[wr]);
        }
      }
    }
  }
}

// ---------------- output projection: out = attn @ Wo^T + bo (f32) ----------------
__global__ __launch_bounds__(256) void gemm_out(
    const _Float16* __restrict__ attn, const _Float16* __restrict__ wob,
    const float* __restrict__ bo, float* __restrict__ out) {
  __shared__ __attribute__((aligned(16))) _Float16 As[128 * 32];
  __shared__ __attribute__((aligned(16))) _Float16 Bs[128 * 32];
  const int sub = blockIdx.x;
  const int i0 = (sub >> 3) * 128, j0 = (sub & 7) * 128;
  f32x4 acc[4][4];
#pragma unroll
  for (int a = 0; a < 4; a++)
#pragma unroll
    for (int b = 0; b < 4; b++) acc[a][b] = (f32x4){0.f, 0.f, 0.f, 0.f};

  gemm_mainloop(attn, wob, i0, j0, As, Bs, acc);

  const int tid = threadIdx.x;
  const int wid = tid >> 6, lane = tid & 63;
  const int lr = lane & 15, lg = lane >> 4;
  const int wm = wid >> 1, wn = wid & 1;
#pragma unroll
  for (int mt = 0; mt < 4; mt++) {
#pragma unroll
    for (int nt = 0; nt < 4; nt++) {
      int i = i0 + wm * 64 + mt * 16 + 4 * lg;
      int j = j0 + wn * 64 + nt * 16 + lr;
      float bj = bo[j];
#pragma unroll
      for (int r = 0; r < 4; r++)
        out[(size_t)(i + r) * HDIM + j] = acc[mt][nt][r] + bj;
    }
  }
}

// ---------------- flash attention v7 ----------------
// v6 + (1) max3/tree max, (2) 4 partial lsums (tree adds), (3) exp2->pack->PV
// interleaved per kf half, (4) s_setprio(1) around MFMA clusters, (5) XCD-aware
// block remap: 1D grid 512 = (xcd 8) x (qb 16 x bh-sub 4); the 16 q-blocks of
// each bh land on one XCD -> K/V L2-resident per XCD.
__global__ __launch_bounds__(512) void attn_kernel(
    const _Float16* __restrict__ Q, const _Float16* __restrict__ K,
    const _Float16* __restrict__ VT, _Float16* __restrict__ AO) {
  const int g = blockIdx.x;
  const int xcd = g & 7, idx = g >> 3;
  const int qb = idx & 15;
  const int bh = xcd * 4 + (idx >> 4);
  const int tid = threadIdx.x, wv = tid >> 6, lane = tid & 63;
  const int lr = lane & 15, lg = lane >> 4;
  const int q0 = qb * 128 + wv * 16;
  const _Float16* Qh = Q + (size_t)bh * SD * HDD;
  const _Float16* Kh = K + (size_t)bh * SD * HDD;
  const _Float16* Vh = VT + (size_t)bh * HDD * SD;

  __shared__ __attribute__((aligned(16))) _Float16 Ks[2][2][64][32];  // [buf][kf][key][d-half]
  __shared__ __attribute__((aligned(16))) _Float16 Vs[2][2][64][32];  // [buf][kf][d][pos]

  // K staging: wave wv stages kf=wv&1, key-rows (wv>>1)*16..+15 (one 16B instr)
  const int krow = lane >> 2;
  const int kswz = (((lane & 3) ^ ((lane >> 3) & 3)) * 8);
  const int kkf = wv & 1, krb = (wv >> 1) * 16;

  // V staging: wave wv stages d-rows wv*8..wv*8+7 per kf (two 4B instrs each)
  const int m  = lane & 15;
  const int u  = m & 3;
  const int sg = m >> 2;
  const int r4 = lane >> 4;
  const int c2 = (r4 >> 1) & 1;
  const int keyoff_e = 16 * (u >> 1) + 4 * (sg ^ c2)       + 2 * (u & 1);
  const int keyoff_o = 16 * (u >> 1) + 4 * (sg ^ (c2 | 2)) + 2 * (u & 1);
  const _Float16* Vrow[2];
  Vrow[0] = Vh + (size_t)(wv * 8 + 0 + r4) * SD + keyoff_e;
  Vrow[1] = Vh + (size_t)(wv * 8 + 4 + r4) * SD + keyoff_o;

  auto stage = [&](int b, int kv0) {
    const _Float16* gk = Kh + (size_t)(kv0 + krb + krow) * HDD + kkf * 32 + kswz;
    __builtin_amdgcn_global_load_lds(
        (__attribute__((address_space(1))) void*)gk,
        (__attribute__((address_space(3))) void*)(&Ks[b][kkf][krb][0]), 16, 0, 0);
#pragma unroll
    for (int kf = 0; kf < 2; kf++)
#pragma unroll
      for (int i = 0; i < 2; i++) {
        const _Float16* gv = Vrow[i] + kv0 + kf * 32;
        __builtin_amdgcn_global_load_lds(
            (__attribute__((address_space(1))) void*)gv,
            (__attribute__((address_space(3))) void*)(&Vs[b][kf][wv * 8 + i * 4][0]), 4, 0, 0);
      }
  };

  const int fswz = (lg ^ ((lr >> 1) & 3)) * 8;

  // Q fragments (pre-scaled by QSCALE): B-operand, lane lr = q-row q0+lr
  f16x8 qf[2];
#pragma unroll
  for (int kf = 0; kf < 2; kf++)
    qf[kf] = *(const f16x8*)(Qh + (size_t)(q0 + lr) * HDD + kf * 32 + lg * 8);

  f32x4 acc[4];
#pragma unroll
  for (int i = 0; i < 4; i++) acc[i] = (f32x4){0.f, 0.f, 0.f, 0.f};
  float mrun = -1e30f;
  float ls0 = 0.f, ls1 = 0.f, ls2 = 0.f, ls3 = 0.f;

  stage(0, 0);
  int cur = 0;

  for (int t = 0; t < SD / 64; ++t) {
    asm volatile("s_waitcnt vmcnt(0)" ::: "memory");
    __builtin_amdgcn_s_barrier();
    stage(cur ^ 1, ((t + 1) & (SD / 64 - 1)) * 64);

    // ---- S^T = K Q^T: lane = (q=lr), keys 16nt+4lg+r (log2 units) ----
    f32x4 sc[4];
#pragma unroll
    for (int nt = 0; nt < 4; nt++) sc[nt] = (f32x4){0.f, 0.f, 0.f, 0.f};
    __builtin_amdgcn_s_setprio(1);
#pragma unroll
    for (int nt = 0; nt < 4; nt++)
#pragma unroll
      for (int kf = 0; kf < 2; kf++) {
        f16x8 kfr = *(const f16x8*)&Ks[cur][kf][nt * 16 + lr][fswz];
        sc[nt] = mfma_f16(kfr, qf[kf], sc[nt]);  // swapped operands
      }
    __builtin_amdgcn_s_setprio(0);

    // ---- max via max3 tree (depth ~4) ----
    float t0 = fmaxf(fmaxf(sc[0][0], sc[0][1]), sc[0][2]);
    float t1 = fmaxf(fmaxf(sc[0][3], sc[1][0]), sc[1][1]);
    float t2 = fmaxf(fmaxf(sc[1][2], sc[1][3]), sc[2][0]);
    float t3 = fmaxf(fmaxf(sc[2][1], sc[2][2]), sc[2][3]);
    float t4 = fmaxf(fmaxf(sc[3][0], sc[3][1]), sc[3][2]);
    float tm = fmaxf(fmaxf(fmaxf(t0, t1), fmaxf(t2, t3)), fmaxf(t4, sc[3][3]));
    tm = fmaxf(tm, __shfl_xor(tm, 16));
    tm = fmaxf(tm, __shfl_xor(tm, 32));

    if (__any(tm - mrun > 8.0f)) {  // defer-max (THR=8)
      float mn = fmaxf(mrun, tm);
      float fm = exp2f(mrun - mn);
      mrun = mn;
      ls0 *= fm; ls1 *= fm; ls2 *= fm; ls3 *= fm;
#pragma unroll
      for (int ntd = 0; ntd < 4; ntd++)
#pragma unroll
        for (int r = 0; r < 4; r++) acc[ntd][r] *= fm;
    }

    // ---- kf-half 0: exp2 keys 0..31, pack, PV ----
    {
      float p0[4], p1[4];
#pragma unroll
      for (int r = 0; r < 4; r++) p0[r] = exp2f(sc[0][r] - mrun);
#pragma unroll
      for (int r = 0; r < 4; r++) p1[r] = exp2f(sc[1][r] - mrun);
      ls0 += (p0[0] + p0[1]) + (p0[2] + p0[3]);
      ls1 += (p1[0] + p1[1]) + (p1[2] + p1[3]);
      unsigned int pw[4];
      pw[0] = pk2h(p0[0], p0[1]); pw[1] = pk2h(p0[2], p0[3]);
      pw[2] = pk2h(p1[0], p1[1]); pw[3] = pk2h(p1[2], p1[3]);
      f16x8 pb = __builtin_bit_cast(f16x8, *(unsigned int(*)[4])pw);
      __builtin_amdgcn_s_setprio(1);
#pragma unroll
      for (int ntd = 0; ntd < 4; ntd++) {
        f16x8 vf = *(const f16x8*)&Vs[cur][0][ntd * 16 + lr][fswz];
        acc[ntd] = mfma_f16(vf, pb, acc[ntd]);
      }
      __builtin_amdgcn_s_setprio(0);
    }
    // ---- kf-half 1: exp2 keys 32..63, pack, PV (overlaps prev MFMAs) ----
    {
      float p0[4], p1[4];
#pragma unroll
      for (int r = 0; r < 4; r++) p0[r] = exp2f(sc[2][r] - mrun);
#pragma unroll
      for (int r = 0; r < 4; r++) p1[r] = exp2f(sc[3][r] - mrun);
      ls2 += (p0[0] + p0[1]) + (p0[2] + p0[3]);
      ls3 += (p1[0] + p1[1]) + (p1[2] + p1[3]);
      unsigned int pw[4];
      pw[0] = pk2h(p0[0], p0[1]); pw[1] = pk2h(p0[2], p0[3]);
      pw[2] = pk2h(p1[0], p1[1]); pw[3] = pk2h(p1[2], p1[3]);
      f16x8 pb = __builtin_bit_cast(f16x8, *(unsigned int(*)[4])pw);
      __builtin_amdgcn_s_setprio(1);
#pragma unroll
      for (int ntd = 0; ntd < 4; ntd++) {
        f16x8 vf = *(const f16x8*)&Vs[cur][1][ntd * 16 + lr][fswz];
        acc[ntd] = mfma_f16(vf, pb, acc[ntd]);
      }
      __builtin_amdgcn_s_setprio(0);
    }
    cur ^= 1;
  }

  // ---- epilogue: merge partials, cross-lane reduce, normalize, write ----
  float lsum = (ls0 + ls1) + (ls2 + ls3);
  lsum += __shfl_xor(lsum, 16);
  lsum += __shfl_xor(lsum, 32);
  float inv = 1.0f / lsum;

  const int b = bh >> 4, h = bh & 15;
  _Float16* aoRow = AO + (size_t)(b * SD + q0 + lr) * HDIM + h * 64;
#pragma unroll
  for (int ntd = 0; ntd < 4; ntd++) {
    f16x4 o;
#pragma unroll
    for (int r = 0; r < 4; r++) o[r] = (_Float16)(acc[ntd][r] * inv);
    *(f16x4*)(aoRow + ntd * 16 + 4 * lg) = o;
  }
}

extern "C" void kernel_launch(void* const* d_in, const int* in_sizes, int n_in,
                              void* d_out, int out_size, void* d_ws, size_t ws_size,
                              hipStream_t stream) {
  const float* x  = (const float*)d_in[0];
  const float* Wq = (const float*)d_in[1];
  const float* bq = (const float*)d_in[2];
  const float* Wk = (const float*)d_in[3];
  const float* bk = (const float*)d_in[4];
  const float* Wv = (const float*)d_in[5];
  const float* bv = (const float*)d_in[6];
  const float* Wo = (const float*)d_in[7];
  const float* bo = (const float*)d_in[8];
  float* out = (float*)d_out;

  _Float16* xb  = (_Float16*)d_ws;            // 4M
  _Float16* wqb = xb + 4 * 1024 * 1024;       // 1M
  _Float16* wkb = wqb + 1024 * 1024;
  _Float16* wvb = wkb + 1024 * 1024;
  _Float16* wob = wvb + 1024 * 1024;
  _Float16* Qb  = wob + 1024 * 1024;          // 4M  [bh][s][d]  (pre-scaled)
  _Float16* Kb  = Qb + 4 * 1024 * 1024;       // 4M  [bh][s][d]
  _Float16* Vt  = Kb + 4 * 1024 * 1024;       // 4M  [bh][d][s]
  _Float16* AOb = Vt + 4 * 1024 * 1024;       // 4M  [token][H]

  convert_kernel<<<dim3(1024), dim3(256), 0, stream>>>(x, Wq, Wk, Wv, Wo, xb);
  gemm_qkv<<<dim3(768), dim3(256), 0, stream>>>(xb, wqb, wkb, wvb, bq, bk, bv, Qb, Kb, Vt);
  attn_kernel<<<dim3(512), dim3(512), 0, stream>>>(Qb, Kb, Vt, AOb);
  gemm_out<<<dim3(256), dim3(256), 0, stream>>>(AOb, wob, bo, out);
}